// Round 2
// baseline (2474.532 us; speedup 1.0000x reference)
//
#include <hip/hip_runtime.h>
#include <math.h>

// Problem constants
#define NN 50000      // nodes
#define NE 800000     // edges
#define HD 512        // hidden
#define GN_EPS 1e-5f

typedef __attribute__((ext_vector_type(4))) float f4;
typedef unsigned short u16;
typedef __attribute__((ext_vector_type(4))) unsigned short us4;
typedef __attribute__((ext_vector_type(8))) unsigned short us8;

static __device__ __forceinline__ float elu1(float v){ return v > 0.f ? v : expm1f(v); }

static __device__ __forceinline__ float bf2f(u16 u){
  union { unsigned int i; float f; } v; v.i = ((unsigned int)u) << 16; return v.f;
}
static __device__ __forceinline__ u16 f2bf(float f){
  union { float f; unsigned int i; } v; v.f = f;
  unsigned int b = v.i;
  b += 0x7FFFu + ((b >> 16) & 1u);   // round-to-nearest-even
  return (u16)(b >> 16);
}

// ---------------- CSR build ----------------
__global__ void k_deg(const int* __restrict__ dst, const float* __restrict__ w,
                      float* __restrict__ deg, int* __restrict__ cnt) {
  int e = blockIdx.x*256 + threadIdx.x;
  if (e < NE) {
    int d = dst[e];
    atomicAdd(&deg[d], w[e]);
    atomicAdd(&cnt[d], 1);
  }
}

__global__ void k_dinv(float* __restrict__ deg) {
  int n = blockIdx.x*256 + threadIdx.x;
  if (n < NN) { float d = deg[n]; deg[n] = d > 0.f ? rsqrtf(d) : 0.f; }
}

// single-block scan -> exclusive row_ptr
__global__ void __launch_bounds__(1024) k_scan(const int* __restrict__ cnt, int* __restrict__ row_ptr) {
  __shared__ int sh[1024];
  __shared__ int carry_sh;
  int t = threadIdx.x;
  if (t == 0) carry_sh = 0;
  __syncthreads();
  for (int base = 0; base < NN; base += 1024) {
    int i = base + t;
    int v = (i < NN) ? cnt[i] : 0;
    sh[t] = v; __syncthreads();
    for (int off = 1; off < 1024; off <<= 1) {
      int x = (t >= off) ? sh[t-off] : 0;
      __syncthreads();
      sh[t] += x;
      __syncthreads();
    }
    if (i < NN) row_ptr[i+1] = carry_sh + sh[t];
    __syncthreads();
    if (t == 0) carry_sh += sh[1023];
    __syncthreads();
  }
  if (t == 0) row_ptr[0] = 0;
}

__global__ void k_fill(const int* __restrict__ src, const int* __restrict__ dst,
                       const float* __restrict__ w, const float* __restrict__ dinv,
                       const int* __restrict__ row_ptr, int* __restrict__ cursor,
                       int* __restrict__ csr_src, float* __restrict__ csr_norm) {
  int e = blockIdx.x*256 + threadIdx.x;
  if (e < NE) {
    int s = src[e], d = dst[e];
    int pos = atomicAdd(&cursor[d], 1);
    int idx = row_ptr[d] + pos;
    csr_src[idx] = s;
    csr_norm[idx] = dinv[s] * w[e] * dinv[d];
  }
}

// ---------------- width-4 propagation (layers 1 & 3), all f32 ----------------
__global__ void k_prop4(const int* __restrict__ row_ptr, const int* __restrict__ csr_src,
                        const float* __restrict__ csr_norm,
                        const f4* __restrict__ in1, const f4* __restrict__ in2,
                        const f4* __restrict__ base, const float* __restrict__ bias,
                        f4* __restrict__ out) {
  int n = blockIdx.x*256 + threadIdx.x;
  if (n >= NN) return;
  f4 acc = {0.f,0.f,0.f,0.f};
  int e0 = row_ptr[n], e1 = row_ptr[n+1];
  if (in2) {
    for (int e = e0; e < e1; ++e) {
      int s = csr_src[e]; float wv = csr_norm[e];
      acc += wv * (in1[s] + in2[s]);
    }
  } else {
    for (int e = e0; e < e1; ++e) {
      int s = csr_src[e]; float wv = csr_norm[e];
      acc += wv * in1[s];
    }
  }
  if (base) acc += base[n];
  if (bias) { acc[0]+=bias[0]; acc[1]+=bias[1]; acc[2]+=bias[2]; acc[3]+=bias[3]; }
  out[n] = acc;
}

// ---------------- width-512 propagation on bf16 features ----------------
__global__ void __launch_bounds__(128) k_prop512_bf(
    const int* __restrict__ row_ptr, const int* __restrict__ csr_src,
    const float* __restrict__ csr_norm,
    const u16* __restrict__ in, u16* __restrict__ out) {
  int n = blockIdx.x;
  int c4 = threadIdx.x * 4;
  f4 acc = {0.f,0.f,0.f,0.f};
  int e0 = row_ptr[n], e1 = row_ptr[n+1];
  for (int e = e0; e < e1; ++e) {
    int s = csr_src[e]; float wv = csr_norm[e];
    us4 v = *reinterpret_cast<const us4*>(in + (size_t)s*HD + c4);
    acc[0] += wv*bf2f(v[0]); acc[1] += wv*bf2f(v[1]);
    acc[2] += wv*bf2f(v[2]); acc[3] += wv*bf2f(v[3]);
  }
  us4 o;
  o[0]=f2bf(acc[0]); o[1]=f2bf(acc[1]); o[2]=f2bf(acc[2]); o[3]=f2bf(acc[3]);
  *reinterpret_cast<us4*>(out + (size_t)n*HD + c4) = o;
}

// ---------------- layer-1 combine: [N,16] x W1[4,4,512] + b1 -> ELU -> act (f32) ----------------
__global__ void __launch_bounds__(128) k_combine1(
    const f4* __restrict__ x, const f4* __restrict__ h1, const f4* __restrict__ h2,
    const f4* __restrict__ h3, const float* __restrict__ W1, const float* __restrict__ b1,
    float* __restrict__ act) {
  int n = blockIdx.x;
  int j = threadIdx.x * 4;
  f4 h[4];
  h[0] = x[n]; h[1] = h1[n]; h[2] = h2[n]; h[3] = h3[n];
  f4 acc = *reinterpret_cast<const f4*>(b1 + j);
  #pragma unroll
  for (int k = 0; k < 4; ++k)
    #pragma unroll
    for (int f = 0; f < 4; ++f) {
      f4 wv = *reinterpret_cast<const f4*>(W1 + (size_t)(k*4 + f)*HD + j);
      acc += h[k][f] * wv;
    }
  #pragma unroll
  for (int q = 0; q < 4; ++q) acc[q] = elu1(acc[q]);
  *reinterpret_cast<f4*>(act + (size_t)n*HD + j) = acc;
}

// ---------------- per-channel stats on f32 (optionally fused bias+ELU writeback) ----------------
__global__ void __launch_bounds__(256) k_stats(
    float* __restrict__ xio, const float* __restrict__ bias, int do_elu,
    float* __restrict__ s1, float* __restrict__ s2) {
  int c = blockIdx.x*256 + threadIdx.x;   // 0..511 over gridDim.x==2
  float sum = 0.f, sq = 0.f;
  float b = bias ? bias[c] : 0.f;
  for (int n = blockIdx.y; n < NN; n += gridDim.y) {
    float v = xio[(size_t)n*HD + c];
    if (do_elu) { v += b; v = elu1(v); xio[(size_t)n*HD + c] = v; }
    sum += v; sq += v*v;
  }
  atomicAdd(&s1[c], sum);
  atomicAdd(&s2[c], sq);
}

// ---------------- GraphNorm normalize: f32 in-place ----------------
__global__ void k_gnorm(float* __restrict__ xio, const float* __restrict__ s1,
                        const float* __restrict__ s2, const float* __restrict__ gw,
                        const float* __restrict__ gb, const float* __restrict__ ga) {
  size_t i = (size_t)blockIdx.x*256 + threadIdx.x;
  size_t total = (size_t)NN*HD/4;
  if (i >= total) return;
  int c = (int)((i*4) % HD);
  f4 v = reinterpret_cast<f4*>(xio)[i];
  #pragma unroll
  for (int q = 0; q < 4; ++q) {
    int cc = c + q;
    float mu  = s1[cc] * (1.f/NN);
    float a   = ga[cc];
    float ex2 = s2[cc] * (1.f/NN);
    float var = ex2 - 2.f*a*mu*mu + a*a*mu*mu;
    float inv = rsqrtf(var + GN_EPS);
    v[q] = gw[cc]*(v[q] - a*mu)*inv + gb[cc];
  }
  reinterpret_cast<f4*>(xio)[i] = v;
}

// ---------------- GraphNorm normalize: f32 in -> bf16 out ----------------
__global__ void k_gnorm_tobf(const float* __restrict__ xin, u16* __restrict__ xout,
                             const float* __restrict__ s1, const float* __restrict__ s2,
                             const float* __restrict__ gw, const float* __restrict__ gb,
                             const float* __restrict__ ga) {
  size_t i = (size_t)blockIdx.x*256 + threadIdx.x;
  size_t total = (size_t)NN*HD/4;
  if (i >= total) return;
  int c = (int)((i*4) % HD);
  f4 v = *reinterpret_cast<const f4*>(xin + i*4);
  us4 o;
  #pragma unroll
  for (int q = 0; q < 4; ++q) {
    int cc = c + q;
    float mu  = s1[cc] * (1.f/NN);
    float a   = ga[cc];
    float ex2 = s2[cc] * (1.f/NN);
    float var = ex2 - 2.f*a*mu*mu + a*a*mu*mu;
    float inv = rsqrtf(var + GN_EPS);
    o[q] = f2bf(gw[cc]*(v[q] - a*mu)*inv + gb[cc]);
  }
  *reinterpret_cast<us4*>(xout + i*4) = o;
}

// ---------------- f32-accumulate tiled GEMM, bf16 A: C[M,512] += A[M,512] @ B[512,512] ----------------
#define BM 128
#define BN 128
#define BK 16
__global__ void __launch_bounds__(256) k_gemm_acc(
    const u16* __restrict__ A, const float* __restrict__ B, float* __restrict__ Cmat, int M) {
  __shared__ float As[BK][BM+4];   // k-major, padded
  __shared__ float Bs[BK][BN];
  int t = threadIdx.x;
  int bm = blockIdx.x * BM;
  int bn = blockIdx.y * BN;
  int tm = (t/16)*8;
  int tn = (t%16)*8;
  float acc[8][8] = {};
  for (int k0 = 0; k0 < HD; k0 += BK) {
    {                                          // A tile: 128 rows x 16 k (bf16 -> f32)
      int m  = t / 2;                          // 0..127
      int k8 = (t % 2) * 8;                    // 0 or 8
      int gm = bm + m; if (gm > M-1) gm = M-1;
      us8 av = *reinterpret_cast<const us8*>(A + (size_t)gm*HD + k0 + k8);
      #pragma unroll
      for (int q = 0; q < 8; ++q) As[k8+q][m] = bf2f(av[q]);
    }
    #pragma unroll
    for (int p = 0; p < 2; ++p) {              // B tile: 16x128 (f32)
      int idx = t + p*256;
      int k = idx/32;
      int n4 = (idx%32)*4;
      f4 bv = *reinterpret_cast<const f4*>(B + (size_t)(k0+k)*HD + bn + n4);
      *reinterpret_cast<f4*>(&Bs[k][n4]) = bv;
    }
    __syncthreads();
    #pragma unroll
    for (int k = 0; k < BK; ++k) {
      f4 a0 = *reinterpret_cast<const f4*>(&As[k][tm]);
      f4 a1 = *reinterpret_cast<const f4*>(&As[k][tm+4]);
      f4 b0 = *reinterpret_cast<const f4*>(&Bs[k][tn]);
      f4 b1v = *reinterpret_cast<const f4*>(&Bs[k][tn+4]);
      float av[8] = {a0[0],a0[1],a0[2],a0[3],a1[0],a1[1],a1[2],a1[3]};
      float bv[8] = {b0[0],b0[1],b0[2],b0[3],b1v[0],b1v[1],b1v[2],b1v[3]};
      #pragma unroll
      for (int i = 0; i < 8; ++i)
        #pragma unroll
        for (int jj = 0; jj < 8; ++jj)
          acc[i][jj] += av[i]*bv[jj];
    }
    __syncthreads();
  }
  #pragma unroll
  for (int i = 0; i < 8; ++i) {
    int gm = bm + tm + i;
    if (gm < M) {
      f4* cp = reinterpret_cast<f4*>(Cmat + (size_t)gm*HD + bn + tn);
      f4 c0 = cp[0], c1 = cp[1];
      #pragma unroll
      for (int jj = 0; jj < 4; ++jj) { c0[jj] += acc[i][jj]; c1[jj] += acc[i][4+jj]; }
      cp[0] = c0; cp[1] = c1;
    }
  }
}

// ---------------- layer-3 linears: p_k = act @ W3[k] (wave per node, f32) ----------------
__global__ void __launch_bounds__(256) k_lin3(
    const float* __restrict__ act, const float* __restrict__ W3,
    f4* __restrict__ p0, f4* __restrict__ p1, f4* __restrict__ p2, f4* __restrict__ p3) {
  int wave = threadIdx.x / 64;
  int lane = threadIdx.x % 64;
  int n = blockIdx.x*4 + wave;
  if (n >= NN) return;
  float part[4][4] = {};
  #pragma unroll
  for (int jj = 0; jj < 8; ++jj) {
    int j = lane + jj*64;
    float v = act[(size_t)n*HD + j];
    #pragma unroll
    for (int k = 0; k < 4; ++k) {
      f4 wv = *reinterpret_cast<const f4*>(W3 + ((size_t)k*HD + j)*4);
      #pragma unroll
      for (int c = 0; c < 4; ++c) part[k][c] += v * wv[c];
    }
  }
  #pragma unroll
  for (int k = 0; k < 4; ++k)
    #pragma unroll
    for (int c = 0; c < 4; ++c) {
      float s = part[k][c];
      #pragma unroll
      for (int off = 32; off >= 1; off >>= 1) s += __shfl_xor(s, off, 64);
      part[k][c] = s;
    }
  if (lane == 0) {
    f4 v0 = {part[0][0],part[0][1],part[0][2],part[0][3]};
    f4 v1 = {part[1][0],part[1][1],part[1][2],part[1][3]};
    f4 v2 = {part[2][0],part[2][1],part[2][2],part[2][3]};
    f4 v3 = {part[3][0],part[3][1],part[3][2],part[3][3]};
    p0[n]=v0; p1[n]=v1; p2[n]=v2; p3[n]=v3;
  }
}

// ---------------- host launch ----------------
extern "C" void kernel_launch(void* const* d_in, const int* in_sizes, int n_in,
                              void* d_out, int out_size, void* d_ws, size_t ws_size,
                              hipStream_t stream) {
  const float* x   = (const float*)d_in[0];
  const int*   ei  = (const int*)d_in[1];
  const int*   src = ei;
  const int*   dst = ei + NE;
  const float* w   = (const float*)d_in[2];
  const float* W1  = (const float*)d_in[3];
  const float* b1  = (const float*)d_in[4];
  const float* W2  = (const float*)d_in[5];
  const float* b2  = (const float*)d_in[6];
  const float* W3  = (const float*)d_in[7];
  const float* b3  = (const float*)d_in[8];
  const float* g1w = (const float*)d_in[9];
  const float* g1b = (const float*)d_in[10];
  const float* g1a = (const float*)d_in[11];
  const float* g2w = (const float*)d_in[12];
  const float* g2b = (const float*)d_in[13];
  const float* g2a = (const float*)d_in[14];

  char* p = (char*)d_ws;
  auto alloc = [&](size_t bytes) -> void* {
    void* r = (void*)p;
    p += (bytes + 255) & ~(size_t)255;
    return r;
  };
  // small buffers (~14.7 MB)
  float* deg      = (float*)alloc(NN*4);          // becomes dinv in place
  int*   cnt      = (int*)  alloc(NN*4);
  int*   row_ptr  = (int*)  alloc((NN+1)*4);
  int*   cursor   = (int*)  alloc(NN*4);
  int*   csr_src  = (int*)  alloc((size_t)NE*4);
  float* csr_nrm  = (float*)alloc((size_t)NE*4);
  f4*    h1       = (f4*)   alloc((size_t)NN*16);
  f4*    h2       = (f4*)   alloc((size_t)NN*16);
  f4*    h3       = (f4*)   alloc((size_t)NN*16);
  f4*    p0       = (f4*)   alloc((size_t)NN*16);
  f4*    p1       = (f4*)   alloc((size_t)NN*16);
  f4*    p2       = (f4*)   alloc((size_t)NN*16);
  f4*    p3       = (f4*)   alloc((size_t)NN*16);
  f4*    t1       = (f4*)   alloc((size_t)NN*16);
  f4*    t2       = (f4*)   alloc((size_t)NN*16);
  float* stats    = (float*)alloc(1024*4);        // s1[512], s2[512]
  float* s1 = stats, *s2 = stats + 512;
  // big buffers: 102.4 MB f32 (act1 / out2 shared) + 2 x 51.2 MB bf16
  float* bigf     = (float*)alloc((size_t)NN*HD*4);   // act1 then out2
  u16*   bfA      = (u16*)  alloc((size_t)NN*HD*2);
  u16*   bfB      = (u16*)  alloc((size_t)NN*HD*2);
  // total ~= 220 MB

  const int TPB = 256;
  int gridE = (NE + TPB - 1)/TPB;
  int gridN = (NN + TPB - 1)/TPB;
  int gridNorm = (int)(((size_t)NN*HD/4 + 255)/256);

  // CSR + norm
  hipMemsetAsync(deg, 0, NN*4, stream);
  hipMemsetAsync(cnt, 0, NN*4, stream);
  k_deg<<<gridE, TPB, 0, stream>>>(dst, w, deg, cnt);
  k_dinv<<<gridN, TPB, 0, stream>>>(deg);
  k_scan<<<1, 1024, 0, stream>>>(cnt, row_ptr);
  hipMemsetAsync(cursor, 0, NN*4, stream);
  k_fill<<<gridE, TPB, 0, stream>>>(src, dst, w, deg, row_ptr, cursor, csr_src, csr_nrm);

  // Layer 1: hops on width-4 x, then combine + ELU -> bigf (f32)
  k_prop4<<<gridN, TPB, 0, stream>>>(row_ptr, csr_src, csr_nrm, (const f4*)x, nullptr, nullptr, nullptr, h1);
  k_prop4<<<gridN, TPB, 0, stream>>>(row_ptr, csr_src, csr_nrm, h1, nullptr, nullptr, nullptr, h2);
  k_prop4<<<gridN, TPB, 0, stream>>>(row_ptr, csr_src, csr_nrm, h2, nullptr, nullptr, nullptr, h3);
  k_combine1<<<NN, 128, 0, stream>>>((const f4*)x, h1, h2, h3, W1, b1, bigf);

  // GraphNorm 1: stats on f32, emit normalized bf16 into bfA (frees bigf)
  hipMemsetAsync(stats, 0, 1024*4, stream);
  k_stats<<<dim3(2,128), 256, 0, stream>>>(bigf, nullptr, 0, s1, s2);
  k_gnorm_tobf<<<gridNorm, 256, 0, stream>>>(bigf, bfA, s1, s2, g1w, g1b, g1a);

  // Layer 2: bigf becomes the f32 accumulator out2
  hipMemsetAsync(bigf, 0, (size_t)NN*HD*4, stream);
  dim3 ggrid((NN + BM - 1)/BM, HD/BN);
  k_gemm_acc<<<ggrid, 256, 0, stream>>>(bfA, W2 + 0*(size_t)HD*HD, bigf, NN);
  k_prop512_bf<<<NN, 128, 0, stream>>>(row_ptr, csr_src, csr_nrm, bfA, bfB);
  k_gemm_acc<<<ggrid, 256, 0, stream>>>(bfB, W2 + 1*(size_t)HD*HD, bigf, NN);
  k_prop512_bf<<<NN, 128, 0, stream>>>(row_ptr, csr_src, csr_nrm, bfB, bfA);
  k_gemm_acc<<<ggrid, 256, 0, stream>>>(bfA, W2 + 2*(size_t)HD*HD, bigf, NN);
  k_prop512_bf<<<NN, 128, 0, stream>>>(row_ptr, csr_src, csr_nrm, bfA, bfB);
  k_gemm_acc<<<ggrid, 256, 0, stream>>>(bfB, W2 + 3*(size_t)HD*HD, bigf, NN);

  // bias + ELU fused into stats pass, then GraphNorm 2 (f32 in place)
  hipMemsetAsync(stats, 0, 1024*4, stream);
  k_stats<<<dim3(2,128), 256, 0, stream>>>(bigf, b2, 1, s1, s2);
  k_gnorm<<<gridNorm, 256, 0, stream>>>(bigf, s1, s2, g2w, g2b, g2a);

  // Layer 3: narrow linears, then Horner with width-4 propagations
  k_lin3<<<(NN+3)/4, 256, 0, stream>>>(bigf, W3, p0, p1, p2, p3);
  k_prop4<<<gridN, TPB, 0, stream>>>(row_ptr, csr_src, csr_nrm, p3, nullptr, nullptr, nullptr, t1);
  k_prop4<<<gridN, TPB, 0, stream>>>(row_ptr, csr_src, csr_nrm, p2, t1, nullptr, nullptr, t2);
  k_prop4<<<gridN, TPB, 0, stream>>>(row_ptr, csr_src, csr_nrm, p1, t2, p0, b3, (f4*)d_out);
}

// Round 3
// 1530.810 us; speedup vs baseline: 1.6165x; 1.6165x over previous
//
#include <hip/hip_runtime.h>
#include <math.h>

// Problem constants
#define NN 50000      // nodes
#define NE 800000     // edges
#define HD 512        // hidden
#define GN_EPS 1e-5f

typedef __attribute__((ext_vector_type(4))) float f4;
typedef __attribute__((ext_vector_type(4))) float f32x4;
typedef __attribute__((ext_vector_type(8))) short short8;
typedef unsigned short u16;
typedef __attribute__((ext_vector_type(4))) unsigned short us4;
typedef __attribute__((ext_vector_type(8))) unsigned short us8;

static __device__ __forceinline__ float elu1(float v){ return v > 0.f ? v : expm1f(v); }

static __device__ __forceinline__ float bf2f(u16 u){
  union { unsigned int i; float f; } v; v.i = ((unsigned int)u) << 16; return v.f;
}
static __device__ __forceinline__ u16 f2bf(float f){
  union { float f; unsigned int i; } v; v.f = f;
  unsigned int b = v.i;
  b += 0x7FFFu + ((b >> 16) & 1u);   // round-to-nearest-even
  return (u16)(b >> 16);
}

// ---------------- CSR build ----------------
__global__ void k_deg(const int* __restrict__ dst, const float* __restrict__ w,
                      float* __restrict__ deg, int* __restrict__ cnt) {
  int e = blockIdx.x*256 + threadIdx.x;
  if (e < NE) {
    int d = dst[e];
    atomicAdd(&deg[d], w[e]);
    atomicAdd(&cnt[d], 1);
  }
}

__global__ void k_dinv(float* __restrict__ deg) {
  int n = blockIdx.x*256 + threadIdx.x;
  if (n < NN) { float d = deg[n]; deg[n] = d > 0.f ? rsqrtf(d) : 0.f; }
}

// single-block scan -> exclusive row_ptr
__global__ void __launch_bounds__(1024) k_scan(const int* __restrict__ cnt, int* __restrict__ row_ptr) {
  __shared__ int sh[1024];
  __shared__ int carry_sh;
  int t = threadIdx.x;
  if (t == 0) carry_sh = 0;
  __syncthreads();
  for (int base = 0; base < NN; base += 1024) {
    int i = base + t;
    int v = (i < NN) ? cnt[i] : 0;
    sh[t] = v; __syncthreads();
    for (int off = 1; off < 1024; off <<= 1) {
      int x = (t >= off) ? sh[t-off] : 0;
      __syncthreads();
      sh[t] += x;
      __syncthreads();
    }
    if (i < NN) row_ptr[i+1] = carry_sh + sh[t];
    __syncthreads();
    if (t == 0) carry_sh += sh[1023];
    __syncthreads();
  }
  if (t == 0) row_ptr[0] = 0;
}

__global__ void k_fill(const int* __restrict__ src, const int* __restrict__ dst,
                       const float* __restrict__ w, const float* __restrict__ dinv,
                       const int* __restrict__ row_ptr, int* __restrict__ cursor,
                       int* __restrict__ csr_src, float* __restrict__ csr_norm) {
  int e = blockIdx.x*256 + threadIdx.x;
  if (e < NE) {
    int s = src[e], d = dst[e];
    int pos = atomicAdd(&cursor[d], 1);
    int idx = row_ptr[d] + pos;
    csr_src[idx] = s;
    csr_norm[idx] = dinv[s] * w[e] * dinv[d];
  }
}

// ---------------- width-4 propagation (layers 1 & 3), all f32 ----------------
__global__ void k_prop4(const int* __restrict__ row_ptr, const int* __restrict__ csr_src,
                        const float* __restrict__ csr_norm,
                        const f4* __restrict__ in1, const f4* __restrict__ in2,
                        const f4* __restrict__ base, const float* __restrict__ bias,
                        f4* __restrict__ out) {
  int n = blockIdx.x*256 + threadIdx.x;
  if (n >= NN) return;
  f4 acc = {0.f,0.f,0.f,0.f};
  int e0 = row_ptr[n], e1 = row_ptr[n+1];
  if (in2) {
    for (int e = e0; e < e1; ++e) {
      int s = csr_src[e]; float wv = csr_norm[e];
      acc += wv * (in1[s] + in2[s]);
    }
  } else {
    for (int e = e0; e < e1; ++e) {
      int s = csr_src[e]; float wv = csr_norm[e];
      acc += wv * in1[s];
    }
  }
  if (base) acc += base[n];
  if (bias) { acc[0]+=bias[0]; acc[1]+=bias[1]; acc[2]+=bias[2]; acc[3]+=bias[3]; }
  out[n] = acc;
}

// ---------------- width-512 propagation on bf16, one wave per node ----------------
__global__ void __launch_bounds__(256) k_prop512_bf(
    const int* __restrict__ row_ptr, const int* __restrict__ csr_src,
    const float* __restrict__ csr_norm,
    const u16* __restrict__ in, u16* __restrict__ out) {
  int wv = threadIdx.x >> 6;
  int l  = threadIdx.x & 63;
  int n = blockIdx.x*4 + wv;
  if (n >= NN) return;
  int e0 = row_ptr[n], e1 = row_ptr[n+1];
  float acc[8] = {0.f,0.f,0.f,0.f,0.f,0.f,0.f,0.f};
  const u16* basep = in + l*8;
  for (int e = e0; e < e1; ++e) {
    int s = csr_src[e]; float wn = csr_norm[e];
    us8 v = *reinterpret_cast<const us8*>(basep + (size_t)s*HD);
    #pragma unroll
    for (int q = 0; q < 8; ++q) acc[q] += wn * bf2f(v[q]);
  }
  us8 o;
  #pragma unroll
  for (int q = 0; q < 8; ++q) o[q] = f2bf(acc[q]);
  *reinterpret_cast<us8*>(out + (size_t)n*HD + l*8) = o;
}

// ---------------- layer-1 combine: [N,16] x W1[4,4,512] + b1 -> ELU -> act (f32) ----------------
__global__ void __launch_bounds__(128) k_combine1(
    const f4* __restrict__ x, const f4* __restrict__ h1, const f4* __restrict__ h2,
    const f4* __restrict__ h3, const float* __restrict__ W1, const float* __restrict__ b1,
    float* __restrict__ act) {
  int n = blockIdx.x;
  int j = threadIdx.x * 4;
  f4 h[4];
  h[0] = x[n]; h[1] = h1[n]; h[2] = h2[n]; h[3] = h3[n];
  f4 acc = *reinterpret_cast<const f4*>(b1 + j);
  #pragma unroll
  for (int k = 0; k < 4; ++k)
    #pragma unroll
    for (int f = 0; f < 4; ++f) {
      f4 wv = *reinterpret_cast<const f4*>(W1 + (size_t)(k*4 + f)*HD + j);
      acc += h[k][f] * wv;
    }
  #pragma unroll
  for (int q = 0; q < 4; ++q) acc[q] = elu1(acc[q]);
  *reinterpret_cast<f4*>(act + (size_t)n*HD + j) = acc;
}

// ---------------- per-channel stats (optionally fused bias+ELU writeback) ----------------
__global__ void __launch_bounds__(256) k_stats(
    float* __restrict__ xio, const float* __restrict__ bias, int do_elu,
    float* __restrict__ s1, float* __restrict__ s2) {
  int c = blockIdx.x*256 + threadIdx.x;   // 0..511 over gridDim.x==2
  float sum = 0.f, sq = 0.f;
  float b = bias ? bias[c] : 0.f;
  for (int n = blockIdx.y; n < NN; n += gridDim.y) {
    float v = xio[(size_t)n*HD + c];
    if (do_elu) { v += b; v = elu1(v); xio[(size_t)n*HD + c] = v; }
    sum += v; sq += v*v;
  }
  atomicAdd(&s1[c], sum);
  atomicAdd(&s2[c], sq);
}

// ---------------- GraphNorm scale/shift precompute: v_norm = sc*v + sh ----------------
__global__ void k_affine(const float* __restrict__ s1, const float* __restrict__ s2,
                         const float* __restrict__ gw, const float* __restrict__ gb,
                         const float* __restrict__ ga,
                         float* __restrict__ sc, float* __restrict__ sh) {
  int c = blockIdx.x*256 + threadIdx.x;
  if (c >= HD) return;
  float mu = s1[c]*(1.f/NN);
  float a  = ga[c];
  float var = s2[c]*(1.f/NN) - 2.f*a*mu*mu + a*a*mu*mu;
  float inv = rsqrtf(var + GN_EPS);
  sc[c] = gw[c]*inv;
  sh[c] = gb[c] - gw[c]*inv*a*mu;
}

// ---------------- normalize f32 -> bf16 with precomputed sc/sh ----------------
__global__ void k_norm_tobf(const float* __restrict__ xin, u16* __restrict__ xout,
                            const float* __restrict__ sc, const float* __restrict__ sh) {
  size_t i = (size_t)blockIdx.x*256 + threadIdx.x;
  size_t total = (size_t)NN*HD/4;
  if (i >= total) return;
  int c = (int)((i*4) % HD);
  f4 v = *reinterpret_cast<const f4*>(xin + i*4);
  us4 o;
  #pragma unroll
  for (int q = 0; q < 4; ++q) o[q] = f2bf(v[q]*sc[c+q] + sh[c+q]);
  *reinterpret_cast<us4*>(xout + i*4) = o;
}

// ---------------- W2 -> bf16 transposed: Bt[k][out][in] = bf16(W2[k][in][out]) ----------------
__global__ void k_w2t(const float* __restrict__ W2, u16* __restrict__ Bt) {
  size_t idx = (size_t)blockIdx.x*256 + threadIdx.x;
  if (idx >= (size_t)4*HD*HD) return;
  int i = (int)(idx & 511);          // in  (fastest -> coalesced write)
  int o = (int)((idx >> 9) & 511);   // out
  int k = (int)(idx >> 18);
  Bt[idx] = f2bf(W2[((size_t)k*HD + i)*HD + o]);
}

// ---------------- MFMA bf16 GEMM: C[M,512] (+)= A[M,512] @ Bt^T ----------------
// A row-major bf16 [M][512]; Bt row-major bf16 [512(out)][512(k)] (i.e. B transposed)
#define BM 128
#define BN 128
#define BKS 32
#define LDR 40   // padded LDS row length in u16 (32 data + 8 pad = 80B, 16B-aligned)
__global__ void __launch_bounds__(256) k_gemm_mfma(
    const u16* __restrict__ A, const u16* __restrict__ Bt, float* __restrict__ C,
    int M, int accumulate) {
  __shared__ u16 As[BM*LDR];
  __shared__ u16 Bs[BN*LDR];
  int t = threadIdx.x;
  int bm = blockIdx.x * BM;
  int bn = blockIdx.y * BN;
  int w  = t >> 6;
  int l  = t & 63;
  int wr = (w >> 1) * 64;   // wave sub-tile row
  int wc = (w & 1) * 64;    // wave sub-tile col
  int lr = l & 15;
  int lq = l >> 4;

  // staging map: slot s = t + p*256 -> row = s>>2, q = s&3 (16B each), 64B/row contiguous
  int row0 = t >> 2, q0 = t & 3;
  int row1 = row0 + 64;
  int ga0 = bm + row0; if (ga0 >= M) ga0 = M - 1;
  int ga1 = bm + row1; if (ga1 >= M) ga1 = M - 1;
  const u16* Ap0 = A  + (size_t)ga0*HD + q0*8;
  const u16* Ap1 = A  + (size_t)ga1*HD + q0*8;
  const u16* Bp0 = Bt + (size_t)(bn + row0)*HD + q0*8;
  const u16* Bp1 = Bt + (size_t)(bn + row1)*HD + q0*8;

  f32x4 acc[4][4];
  #pragma unroll
  for (int i = 0; i < 4; ++i)
    #pragma unroll
    for (int j = 0; j < 4; ++j) acc[i][j] = (f32x4){0.f,0.f,0.f,0.f};

  us8 ra0 = *reinterpret_cast<const us8*>(Ap0);
  us8 ra1 = *reinterpret_cast<const us8*>(Ap1);
  us8 rb0 = *reinterpret_cast<const us8*>(Bp0);
  us8 rb1 = *reinterpret_cast<const us8*>(Bp1);

  for (int k0 = 0; k0 < HD; k0 += BKS) {
    __syncthreads();   // previous iteration's LDS reads complete
    *reinterpret_cast<us8*>(&As[row0*LDR + q0*8]) = ra0;
    *reinterpret_cast<us8*>(&As[row1*LDR + q0*8]) = ra1;
    *reinterpret_cast<us8*>(&Bs[row0*LDR + q0*8]) = rb0;
    *reinterpret_cast<us8*>(&Bs[row1*LDR + q0*8]) = rb1;
    if (k0 + BKS < HD) {   // prefetch next K-tile (overlaps MFMA below)
      ra0 = *reinterpret_cast<const us8*>(Ap0 + k0 + BKS);
      ra1 = *reinterpret_cast<const us8*>(Ap1 + k0 + BKS);
      rb0 = *reinterpret_cast<const us8*>(Bp0 + k0 + BKS);
      rb1 = *reinterpret_cast<const us8*>(Bp1 + k0 + BKS);
    }
    __syncthreads();   // tile ready
    short8 af[4], bfr[4];
    #pragma unroll
    for (int mi = 0; mi < 4; ++mi)
      af[mi] = *reinterpret_cast<const short8*>(&As[(wr + mi*16 + lr)*LDR + lq*8]);
    #pragma unroll
    for (int ni = 0; ni < 4; ++ni)
      bfr[ni] = *reinterpret_cast<const short8*>(&Bs[(wc + ni*16 + lr)*LDR + lq*8]);
    #pragma unroll
    for (int mi = 0; mi < 4; ++mi)
      #pragma unroll
      for (int ni = 0; ni < 4; ++ni)
        acc[mi][ni] = __builtin_amdgcn_mfma_f32_16x16x32_bf16(af[mi], bfr[ni], acc[mi][ni], 0, 0, 0);
  }

  // epilogue: lane holds col = lr, rows lq*4+r
  #pragma unroll
  for (int mi = 0; mi < 4; ++mi) {
    #pragma unroll
    for (int ni = 0; ni < 4; ++ni) {
      #pragma unroll
      for (int r = 0; r < 4; ++r) {
        int gm = bm + wr + mi*16 + lq*4 + r;
        int gn = bn + wc + ni*16 + lr;
        if (gm < M) {
          float* cp = &C[(size_t)gm*HD + gn];
          *cp = accumulate ? (*cp + acc[mi][ni][r]) : acc[mi][ni][r];
        }
      }
    }
  }
}

// ---------------- layer-3 linears with fused GraphNorm affine ----------------
__global__ void __launch_bounds__(256) k_lin3(
    const float* __restrict__ act, const float* __restrict__ sc, const float* __restrict__ sh,
    const float* __restrict__ W3,
    f4* __restrict__ p0, f4* __restrict__ p1, f4* __restrict__ p2, f4* __restrict__ p3) {
  int wave = threadIdx.x / 64;
  int lane = threadIdx.x % 64;
  int n = blockIdx.x*4 + wave;
  if (n >= NN) return;
  float part[4][4] = {};
  #pragma unroll
  for (int jj = 0; jj < 8; ++jj) {
    int j = lane + jj*64;
    float v = sc[j]*act[(size_t)n*HD + j] + sh[j];
    #pragma unroll
    for (int k = 0; k < 4; ++k) {
      f4 wv = *reinterpret_cast<const f4*>(W3 + ((size_t)k*HD + j)*4);
      #pragma unroll
      for (int c = 0; c < 4; ++c) part[k][c] += v * wv[c];
    }
  }
  #pragma unroll
  for (int k = 0; k < 4; ++k)
    #pragma unroll
    for (int c = 0; c < 4; ++c) {
      float s = part[k][c];
      #pragma unroll
      for (int off = 32; off >= 1; off >>= 1) s += __shfl_xor(s, off, 64);
      part[k][c] = s;
    }
  if (lane == 0) {
    f4 v0 = {part[0][0],part[0][1],part[0][2],part[0][3]};
    f4 v1 = {part[1][0],part[1][1],part[1][2],part[1][3]};
    f4 v2 = {part[2][0],part[2][1],part[2][2],part[2][3]};
    f4 v3 = {part[3][0],part[3][1],part[3][2],part[3][3]};
    p0[n]=v0; p1[n]=v1; p2[n]=v2; p3[n]=v3;
  }
}

// ---------------- host launch ----------------
extern "C" void kernel_launch(void* const* d_in, const int* in_sizes, int n_in,
                              void* d_out, int out_size, void* d_ws, size_t ws_size,
                              hipStream_t stream) {
  const float* x   = (const float*)d_in[0];
  const int*   ei  = (const int*)d_in[1];
  const int*   src = ei;
  const int*   dst = ei + NE;
  const float* w   = (const float*)d_in[2];
  const float* W1  = (const float*)d_in[3];
  const float* b1  = (const float*)d_in[4];
  const float* W2  = (const float*)d_in[5];
  const float* b2  = (const float*)d_in[6];
  const float* W3  = (const float*)d_in[7];
  const float* b3  = (const float*)d_in[8];
  const float* g1w = (const float*)d_in[9];
  const float* g1b = (const float*)d_in[10];
  const float* g1a = (const float*)d_in[11];
  const float* g2w = (const float*)d_in[12];
  const float* g2b = (const float*)d_in[13];
  const float* g2a = (const float*)d_in[14];

  char* p = (char*)d_ws;
  auto alloc = [&](size_t bytes) -> void* {
    void* r = (void*)p;
    p += (bytes + 255) & ~(size_t)255;
    return r;
  };
  // small buffers (~17 MB)
  float* deg      = (float*)alloc(NN*4);
  int*   cnt      = (int*)  alloc(NN*4);
  int*   row_ptr  = (int*)  alloc((NN+1)*4);
  int*   cursor   = (int*)  alloc(NN*4);
  int*   csr_src  = (int*)  alloc((size_t)NE*4);
  float* csr_nrm  = (float*)alloc((size_t)NE*4);
  f4*    h1       = (f4*)   alloc((size_t)NN*16);
  f4*    h2       = (f4*)   alloc((size_t)NN*16);
  f4*    h3       = (f4*)   alloc((size_t)NN*16);
  f4*    p0       = (f4*)   alloc((size_t)NN*16);
  f4*    p1       = (f4*)   alloc((size_t)NN*16);
  f4*    p2       = (f4*)   alloc((size_t)NN*16);
  f4*    p3       = (f4*)   alloc((size_t)NN*16);
  f4*    t1       = (f4*)   alloc((size_t)NN*16);
  f4*    t2       = (f4*)   alloc((size_t)NN*16);
  float* stats    = (float*)alloc(1024*4);
  float* s1 = stats, *s2 = stats + 512;
  float* scb      = (float*)alloc(HD*4);
  float* shb      = (float*)alloc(HD*4);
  u16*   W2T      = (u16*)  alloc((size_t)4*HD*HD*2);   // 2 MB
  // big buffers: 102.4 MB f32 + 2 x 51.2 MB bf16  (~222 MB total)
  float* bigf     = (float*)alloc((size_t)NN*HD*4);
  u16*   bfA      = (u16*)  alloc((size_t)NN*HD*2);
  u16*   bfB      = (u16*)  alloc((size_t)NN*HD*2);

  const int TPB = 256;
  int gridE = (NE + TPB - 1)/TPB;
  int gridN = (NN + TPB - 1)/TPB;
  int gridNorm = (int)(((size_t)NN*HD/4 + 255)/256);

  // CSR + norm
  hipMemsetAsync(deg, 0, NN*4, stream);
  hipMemsetAsync(cnt, 0, NN*4, stream);
  k_deg<<<gridE, TPB, 0, stream>>>(dst, w, deg, cnt);
  k_dinv<<<gridN, TPB, 0, stream>>>(deg);
  k_scan<<<1, 1024, 0, stream>>>(cnt, row_ptr);
  hipMemsetAsync(cursor, 0, NN*4, stream);
  k_fill<<<gridE, TPB, 0, stream>>>(src, dst, w, deg, row_ptr, cursor, csr_src, csr_nrm);
  k_w2t<<<(4*HD*HD + 255)/256, 256, 0, stream>>>(W2, W2T);

  // Layer 1
  k_prop4<<<gridN, TPB, 0, stream>>>(row_ptr, csr_src, csr_nrm, (const f4*)x, nullptr, nullptr, nullptr, h1);
  k_prop4<<<gridN, TPB, 0, stream>>>(row_ptr, csr_src, csr_nrm, h1, nullptr, nullptr, nullptr, h2);
  k_prop4<<<gridN, TPB, 0, stream>>>(row_ptr, csr_src, csr_nrm, h2, nullptr, nullptr, nullptr, h3);
  k_combine1<<<NN, 128, 0, stream>>>((const f4*)x, h1, h2, h3, W1, b1, bigf);

  // GraphNorm 1 -> bf16
  hipMemsetAsync(stats, 0, 1024*4, stream);
  k_stats<<<dim3(2,128), 256, 0, stream>>>(bigf, nullptr, 0, s1, s2);
  k_affine<<<2, 256, 0, stream>>>(s1, s2, g1w, g1b, g1a, scb, shb);
  k_norm_tobf<<<gridNorm, 256, 0, stream>>>(bigf, bfA, scb, shb);

  // Layer 2: MFMA GEMMs interleaved with bf16 hops; bigf is the f32 accumulator
  dim3 ggrid((NN + BM - 1)/BM, HD/BN);
  int gridP = (NN + 3)/4;
  k_gemm_mfma<<<ggrid, 256, 0, stream>>>(bfA, W2T + 0*(size_t)HD*HD, bigf, NN, 0);
  k_prop512_bf<<<gridP, 256, 0, stream>>>(row_ptr, csr_src, csr_nrm, bfA, bfB);
  k_gemm_mfma<<<ggrid, 256, 0, stream>>>(bfB, W2T + 1*(size_t)HD*HD, bigf, NN, 1);
  k_prop512_bf<<<gridP, 256, 0, stream>>>(row_ptr, csr_src, csr_nrm, bfB, bfA);
  k_gemm_mfma<<<ggrid, 256, 0, stream>>>(bfA, W2T + 2*(size_t)HD*HD, bigf, NN, 1);
  k_prop512_bf<<<gridP, 256, 0, stream>>>(row_ptr, csr_src, csr_nrm, bfA, bfB);
  k_gemm_mfma<<<ggrid, 256, 0, stream>>>(bfB, W2T + 3*(size_t)HD*HD, bigf, NN, 1);

  // bias + ELU fused into stats pass; norm affine folded into lin3
  hipMemsetAsync(stats, 0, 1024*4, stream);
  k_stats<<<dim3(2,128), 256, 0, stream>>>(bigf, b2, 1, s1, s2);
  k_affine<<<2, 256, 0, stream>>>(s1, s2, g2w, g2b, g2a, scb, shb);

  // Layer 3: fused-norm narrow linears, then Horner with width-4 propagations
  k_lin3<<<gridP, 256, 0, stream>>>(bigf, scb, shb, W3, p0, p1, p2, p3);
  k_prop4<<<gridN, TPB, 0, stream>>>(row_ptr, csr_src, csr_nrm, p3, nullptr, nullptr, nullptr, t1);
  k_prop4<<<gridN, TPB, 0, stream>>>(row_ptr, csr_src, csr_nrm, p2, t1, nullptr, nullptr, t2);
  k_prop4<<<gridN, TPB, 0, stream>>>(row_ptr, csr_src, csr_nrm, p1, t2, p0, b3, (f4*)d_out);
}

// Round 4
// 1246.364 us; speedup vs baseline: 1.9854x; 1.2282x over previous
//
#include <hip/hip_runtime.h>
#include <math.h>

// Problem constants
#define NN 50000      // nodes
#define NE 800000     // edges
#define HD 512        // hidden
#define GN_EPS 1e-5f
#define NBCHUNK 196   // ceil(NN/256) for scan
#define GRIDM 391     // ceil(NN/128) GEMM grid rows
#define STATS_NB 512  // stats1 partial blocks

typedef __attribute__((ext_vector_type(4))) float f4;
typedef __attribute__((ext_vector_type(4))) float f32x4;
typedef __attribute__((ext_vector_type(8))) short short8;
typedef unsigned short u16;
typedef __attribute__((ext_vector_type(4))) unsigned short us4;
typedef __attribute__((ext_vector_type(8))) unsigned short us8;

static __device__ __forceinline__ float elu1(float v){ return v > 0.f ? v : expm1f(v); }

static __device__ __forceinline__ float bf2f(u16 u){
  union { unsigned int i; float f; } v; v.i = ((unsigned int)u) << 16; return v.f;
}
static __device__ __forceinline__ u16 f2bf(float f){
  union { float f; unsigned int i; } v; v.f = f;
  unsigned int b = v.i;
  b += 0x7FFFu + ((b >> 16) & 1u);   // round-to-nearest-even
  return (u16)(b >> 16);
}

// ---------------- CSR build ----------------
__global__ void k_deg(const int* __restrict__ dst, const float* __restrict__ w,
                      float* __restrict__ deg, int* __restrict__ cnt) {
  int e = blockIdx.x*256 + threadIdx.x;
  if (e < NE) {
    int d = dst[e];
    atomicAdd(&deg[d], w[e]);
    atomicAdd(&cnt[d], 1);
  }
}

__global__ void k_dinv(float* __restrict__ deg) {
  int n = blockIdx.x*256 + threadIdx.x;
  if (n < NN) { float d = deg[n]; deg[n] = d > 0.f ? rsqrtf(d) : 0.f; }
}

// hierarchical scan: chunk-local inclusive -> chunk totals
__global__ void __launch_bounds__(256) k_scanA(const int* __restrict__ cnt,
                                               int* __restrict__ row_ptr,
                                               int* __restrict__ btot) {
  __shared__ int sh[256];
  int t = threadIdx.x, b = blockIdx.x;
  int i = b*256 + t;
  int v = (i < NN) ? cnt[i] : 0;
  sh[t] = v; __syncthreads();
  #pragma unroll
  for (int off = 1; off < 256; off <<= 1) {
    int x = (t >= off) ? sh[t-off] : 0;
    __syncthreads();
    sh[t] += x;
    __syncthreads();
  }
  if (i < NN) row_ptr[i+1] = sh[t];
  if (t == 255) btot[b] = sh[255];
}

__global__ void __launch_bounds__(256) k_scanB(const int* __restrict__ btot,
                                               int* __restrict__ boff) {
  __shared__ int sh[256];
  int t = threadIdx.x;
  int v = (t < NBCHUNK) ? btot[t] : 0;
  sh[t] = v; __syncthreads();
  #pragma unroll
  for (int off = 1; off < 256; off <<= 1) {
    int x = (t >= off) ? sh[t-off] : 0;
    __syncthreads();
    sh[t] += x;
    __syncthreads();
  }
  if (t < NBCHUNK) boff[t] = sh[t] - v;   // exclusive
}

__global__ void __launch_bounds__(256) k_scanC(int* __restrict__ row_ptr,
                                               const int* __restrict__ boff) {
  int t = threadIdx.x, b = blockIdx.x;
  int i = b*256 + t;
  if (i < NN) row_ptr[i+1] += boff[b];
  if (i == 0) row_ptr[0] = 0;
}

__global__ void k_fill(const int* __restrict__ src, const int* __restrict__ dst,
                       const float* __restrict__ w, const float* __restrict__ dinv,
                       const int* __restrict__ row_ptr, int* __restrict__ cursor,
                       int* __restrict__ csr_src, float* __restrict__ csr_norm) {
  int e = blockIdx.x*256 + threadIdx.x;
  if (e < NE) {
    int s = src[e], d = dst[e];
    int pos = atomicAdd(&cursor[d], 1);
    int idx = row_ptr[d] + pos;
    csr_src[idx] = s;
    csr_norm[idx] = dinv[s] * w[e] * dinv[d];
  }
}

// ---------------- width-4 propagation (layers 1 & 3), all f32 ----------------
__global__ void k_prop4(const int* __restrict__ row_ptr, const int* __restrict__ csr_src,
                        const float* __restrict__ csr_norm,
                        const f4* __restrict__ in1, const f4* __restrict__ in2,
                        const f4* __restrict__ base, const float* __restrict__ bias,
                        f4* __restrict__ out) {
  int n = blockIdx.x*256 + threadIdx.x;
  if (n >= NN) return;
  f4 acc = {0.f,0.f,0.f,0.f};
  int e0 = row_ptr[n], e1 = row_ptr[n+1];
  if (in2) {
    for (int e = e0; e < e1; ++e) {
      int s = csr_src[e]; float wv = csr_norm[e];
      acc += wv * (in1[s] + in2[s]);
    }
  } else {
    for (int e = e0; e < e1; ++e) {
      int s = csr_src[e]; float wv = csr_norm[e];
      acc += wv * in1[s];
    }
  }
  if (base) acc += base[n];
  if (bias) { acc[0]+=bias[0]; acc[1]+=bias[1]; acc[2]+=bias[2]; acc[3]+=bias[3]; }
  out[n] = acc;
}

// ---------------- width-512 propagation on bf16, one wave per node ----------------
__global__ void __launch_bounds__(256) k_prop512_bf(
    const int* __restrict__ row_ptr, const int* __restrict__ csr_src,
    const float* __restrict__ csr_norm,
    const u16* __restrict__ in, u16* __restrict__ out) {
  int wv = threadIdx.x >> 6;
  int l  = threadIdx.x & 63;
  int n = blockIdx.x*4 + wv;
  if (n >= NN) return;
  int e0 = row_ptr[n], e1 = row_ptr[n+1];
  float acc[8] = {0.f,0.f,0.f,0.f,0.f,0.f,0.f,0.f};
  const u16* basep = in + l*8;
  for (int e = e0; e < e1; ++e) {
    int s = csr_src[e]; float wn = csr_norm[e];
    us8 v = *reinterpret_cast<const us8*>(basep + (size_t)s*HD);
    #pragma unroll
    for (int q = 0; q < 8; ++q) acc[q] += wn * bf2f(v[q]);
  }
  us8 o;
  #pragma unroll
  for (int q = 0; q < 8; ++q) o[q] = f2bf(acc[q]);
  *reinterpret_cast<us8*>(out + (size_t)n*HD + l*8) = o;
}

// ---------------- layer-1 combine: [N,16] x W1[4,4,512] + b1 -> ELU -> act (f32) ----------------
__global__ void __launch_bounds__(128) k_combine1(
    const f4* __restrict__ x, const f4* __restrict__ h1, const f4* __restrict__ h2,
    const f4* __restrict__ h3, const float* __restrict__ W1, const float* __restrict__ b1,
    float* __restrict__ act) {
  int n = blockIdx.x;
  int j = threadIdx.x * 4;
  f4 h[4];
  h[0] = x[n]; h[1] = h1[n]; h[2] = h2[n]; h[3] = h3[n];
  f4 acc = *reinterpret_cast<const f4*>(b1 + j);
  #pragma unroll
  for (int k = 0; k < 4; ++k)
    #pragma unroll
    for (int f = 0; f < 4; ++f) {
      f4 wv = *reinterpret_cast<const f4*>(W1 + (size_t)(k*4 + f)*HD + j);
      acc += h[k][f] * wv;
    }
  #pragma unroll
  for (int q = 0; q < 4; ++q) acc[q] = elu1(acc[q]);
  *reinterpret_cast<f4*>(act + (size_t)n*HD + j) = acc;
}

// ---------------- stats pass 1: coalesced two-stage column sums ----------------
__global__ void __launch_bounds__(256) k_stats1(
    const float* __restrict__ x, float* __restrict__ pS, float* __restrict__ pQ) {
  __shared__ float sdS[HD], sdQ[HD];
  int t = threadIdx.x;
  int half = t >> 7;
  int c4 = (t & 127) * 4;
  f4 s = {0.f,0.f,0.f,0.f}, q = {0.f,0.f,0.f,0.f};
  for (int r = blockIdx.x*2 + half; r < NN; r += gridDim.x*2) {
    f4 v = *reinterpret_cast<const f4*>(x + (size_t)r*HD + c4);
    s += v; q += v*v;
  }
  if (half) {
    *reinterpret_cast<f4*>(&sdS[c4]) = s;
    *reinterpret_cast<f4*>(&sdQ[c4]) = q;
  }
  __syncthreads();
  if (!half) {
    f4 ts = *reinterpret_cast<f4*>(&sdS[c4]) + s;
    f4 tq = *reinterpret_cast<f4*>(&sdQ[c4]) + q;
    *reinterpret_cast<f4*>(&pS[(size_t)blockIdx.x*HD + c4]) = ts;
    *reinterpret_cast<f4*>(&pQ[(size_t)blockIdx.x*HD + c4]) = tq;
  }
}

// ---------------- reduce partials [nb][512] -> s1,s2 ----------------
__global__ void __launch_bounds__(256) k_reduce(
    const float* __restrict__ pS, const float* __restrict__ pQ, int nb,
    float* __restrict__ s1, float* __restrict__ s2) {
  int c = blockIdx.x*256 + threadIdx.x;
  if (c >= HD) return;
  float a = 0.f, b = 0.f;
  for (int i = 0; i < nb; ++i) {
    a += pS[(size_t)i*HD + c];
    b += pQ[(size_t)i*HD + c];
  }
  s1[c] = a; s2[c] = b;
}

// ---------------- GraphNorm scale/shift precompute: v_norm = sc*v + sh ----------------
__global__ void k_affine(const float* __restrict__ s1, const float* __restrict__ s2,
                         const float* __restrict__ gw, const float* __restrict__ gb,
                         const float* __restrict__ ga,
                         float* __restrict__ sc, float* __restrict__ sh) {
  int c = blockIdx.x*256 + threadIdx.x;
  if (c >= HD) return;
  float mu = s1[c]*(1.f/NN);
  float a  = ga[c];
  float var = s2[c]*(1.f/NN) - 2.f*a*mu*mu + a*a*mu*mu;
  float inv = rsqrtf(var + GN_EPS);
  sc[c] = gw[c]*inv;
  sh[c] = gb[c] - gw[c]*inv*a*mu;
}

// ---------------- normalize f32 -> bf16 with precomputed sc/sh ----------------
__global__ void k_norm_tobf(const float* __restrict__ xin, u16* __restrict__ xout,
                            const float* __restrict__ sc, const float* __restrict__ sh) {
  size_t i = (size_t)blockIdx.x*256 + threadIdx.x;
  size_t total = (size_t)NN*HD/4;
  if (i >= total) return;
  int c = (int)((i*4) % HD);
  f4 v = *reinterpret_cast<const f4*>(xin + i*4);
  f4 scv = *reinterpret_cast<const f4*>(sc + c);
  f4 shv = *reinterpret_cast<const f4*>(sh + c);
  us4 o;
  #pragma unroll
  for (int q = 0; q < 4; ++q) o[q] = f2bf(v[q]*scv[q] + shv[q]);
  *reinterpret_cast<us4*>(xout + i*4) = o;
}

// ---------------- W2 -> bf16 transposed: Bt[k][out][in] = bf16(W2[k][in][out]) ----------------
__global__ void k_w2t(const float* __restrict__ W2, u16* __restrict__ Bt) {
  size_t idx = (size_t)blockIdx.x*256 + threadIdx.x;
  if (idx >= (size_t)4*HD*HD) return;
  int i = (int)(idx & 511);          // in  (fastest -> coalesced write)
  int o = (int)((idx >> 9) & 511);   // out
  int k = (int)(idx >> 18);
  Bt[idx] = f2bf(W2[((size_t)k*HD + i)*HD + o]);
}

// ---------------- MFMA bf16 dual-source GEMM (K=1024): C = A0@B0^T + A1@B1^T ----------------
// FINAL=1: C += ..., then v=elu(C+bias), write v, emit per-channel partial sums.
#define BM 128
#define BN 128
#define BKS 32
#define LDR 40   // padded LDS row length in u16 (32 data + 8 pad = 80B)
template<int FINAL>
__global__ void __launch_bounds__(256) k_gemm2(
    const u16* __restrict__ A0, const u16* __restrict__ A1,
    const u16* __restrict__ B0, const u16* __restrict__ B1,
    float* __restrict__ C, const float* __restrict__ bias,
    float* __restrict__ pS, float* __restrict__ pQ, int M) {
  __shared__ u16 As[BM*LDR];
  __shared__ u16 Bs[BN*LDR];
  __shared__ float sdS[BN], sdQ[BN];
  int t = threadIdx.x;
  int bm = blockIdx.x * BM;
  int bn = blockIdx.y * BN;
  int w  = t >> 6;
  int l  = t & 63;
  int wr = (w >> 1) * 64;
  int wc = (w & 1) * 64;
  int lr = l & 15;
  int lq = l >> 4;

  if (FINAL && t < BN) { sdS[t] = 0.f; sdQ[t] = 0.f; }

  int row0 = t >> 2, q0 = t & 3;
  int row1 = row0 + 64;
  int ga0 = bm + row0; if (ga0 >= M) ga0 = M - 1;
  int ga1 = bm + row1; if (ga1 >= M) ga1 = M - 1;
  const u16* a0p0 = A0 + (size_t)ga0*HD + q0*8;
  const u16* a0p1 = A0 + (size_t)ga1*HD + q0*8;
  const u16* a1p0 = A1 + (size_t)ga0*HD + q0*8;
  const u16* a1p1 = A1 + (size_t)ga1*HD + q0*8;
  const u16* b0p0 = B0 + (size_t)(bn + row0)*HD + q0*8;
  const u16* b0p1 = B0 + (size_t)(bn + row1)*HD + q0*8;
  const u16* b1p0 = B1 + (size_t)(bn + row0)*HD + q0*8;
  const u16* b1p1 = B1 + (size_t)(bn + row1)*HD + q0*8;

  f32x4 acc[4][4];
  #pragma unroll
  for (int i = 0; i < 4; ++i)
    #pragma unroll
    for (int j = 0; j < 4; ++j) acc[i][j] = (f32x4){0.f,0.f,0.f,0.f};

  us8 ra0 = *reinterpret_cast<const us8*>(a0p0);
  us8 ra1 = *reinterpret_cast<const us8*>(a0p1);
  us8 rb0 = *reinterpret_cast<const us8*>(b0p0);
  us8 rb1 = *reinterpret_cast<const us8*>(b0p1);

  for (int k0 = 0; k0 < 2*HD; k0 += BKS) {
    __syncthreads();
    *reinterpret_cast<us8*>(&As[row0*LDR + q0*8]) = ra0;
    *reinterpret_cast<us8*>(&As[row1*LDR + q0*8]) = ra1;
    *reinterpret_cast<us8*>(&Bs[row0*LDR + q0*8]) = rb0;
    *reinterpret_cast<us8*>(&Bs[row1*LDR + q0*8]) = rb1;
    int k1 = k0 + BKS;
    if (k1 < 2*HD) {
      int off = k1 & (HD-1);
      if (k1 < HD) {
        ra0 = *reinterpret_cast<const us8*>(a0p0 + off);
        ra1 = *reinterpret_cast<const us8*>(a0p1 + off);
        rb0 = *reinterpret_cast<const us8*>(b0p0 + off);
        rb1 = *reinterpret_cast<const us8*>(b0p1 + off);
      } else {
        ra0 = *reinterpret_cast<const us8*>(a1p0 + off);
        ra1 = *reinterpret_cast<const us8*>(a1p1 + off);
        rb0 = *reinterpret_cast<const us8*>(b1p0 + off);
        rb1 = *reinterpret_cast<const us8*>(b1p1 + off);
      }
    }
    __syncthreads();
    short8 af[4], bfr[4];
    #pragma unroll
    for (int mi = 0; mi < 4; ++mi)
      af[mi] = *reinterpret_cast<const short8*>(&As[(wr + mi*16 + lr)*LDR + lq*8]);
    #pragma unroll
    for (int ni = 0; ni < 4; ++ni)
      bfr[ni] = *reinterpret_cast<const short8*>(&Bs[(wc + ni*16 + lr)*LDR + lq*8]);
    #pragma unroll
    for (int mi = 0; mi < 4; ++mi)
      #pragma unroll
      for (int ni = 0; ni < 4; ++ni)
        acc[mi][ni] = __builtin_amdgcn_mfma_f32_16x16x32_bf16(af[mi], bfr[ni], acc[mi][ni], 0, 0, 0);
  }

  if (!FINAL) {
    #pragma unroll
    for (int mi = 0; mi < 4; ++mi)
      #pragma unroll
      for (int ni = 0; ni < 4; ++ni)
        #pragma unroll
        for (int r = 0; r < 4; ++r) {
          int gm = bm + wr + mi*16 + lq*4 + r;
          int gn = bn + wc + ni*16 + lr;
          if (gm < M) C[(size_t)gm*HD + gn] = acc[mi][ni][r];
        }
  } else {
    float psum[4] = {0.f,0.f,0.f,0.f}, qsum[4] = {0.f,0.f,0.f,0.f};
    #pragma unroll
    for (int ni = 0; ni < 4; ++ni) {
      int gn = bn + wc + ni*16 + lr;
      float bgn = bias[gn];
      #pragma unroll
      for (int mi = 0; mi < 4; ++mi)
        #pragma unroll
        for (int r = 0; r < 4; ++r) {
          int gm = bm + wr + mi*16 + lq*4 + r;
          if (gm < M) {
            float* cp = &C[(size_t)gm*HD + gn];
            float v = elu1(*cp + acc[mi][ni][r] + bgn);
            *cp = v;
            psum[ni] += v; qsum[ni] += v*v;
          }
        }
    }
    #pragma unroll
    for (int ni = 0; ni < 4; ++ni) {
      psum[ni] += __shfl_xor(psum[ni], 16, 64);
      psum[ni] += __shfl_xor(psum[ni], 32, 64);
      qsum[ni] += __shfl_xor(qsum[ni], 16, 64);
      qsum[ni] += __shfl_xor(qsum[ni], 32, 64);
    }
    if (lq == 0) {
      #pragma unroll
      for (int ni = 0; ni < 4; ++ni) {
        atomicAdd(&sdS[wc + ni*16 + lr], psum[ni]);   // exactly 2 contribs/slot
        atomicAdd(&sdQ[wc + ni*16 + lr], qsum[ni]);
      }
    }
    __syncthreads();
    if (t < BN) {
      pS[(size_t)blockIdx.x*HD + bn + t] = sdS[t];
      pQ[(size_t)blockIdx.x*HD + bn + t] = sdQ[t];
    }
  }
}

// ---------------- layer-3 linears with fused GraphNorm affine ----------------
__global__ void __launch_bounds__(256) k_lin3(
    const float* __restrict__ act, const float* __restrict__ sc, const float* __restrict__ sh,
    const float* __restrict__ W3,
    f4* __restrict__ p0, f4* __restrict__ p1, f4* __restrict__ p2, f4* __restrict__ p3) {
  int wave = threadIdx.x / 64;
  int lane = threadIdx.x % 64;
  int n = blockIdx.x*4 + wave;
  if (n >= NN) return;
  float part[4][4] = {};
  #pragma unroll
  for (int jj = 0; jj < 8; ++jj) {
    int j = lane + jj*64;
    float v = sc[j]*act[(size_t)n*HD + j] + sh[j];
    #pragma unroll
    for (int k = 0; k < 4; ++k) {
      f4 wv = *reinterpret_cast<const f4*>(W3 + ((size_t)k*HD + j)*4);
      #pragma unroll
      for (int c = 0; c < 4; ++c) part[k][c] += v * wv[c];
    }
  }
  #pragma unroll
  for (int k = 0; k < 4; ++k)
    #pragma unroll
    for (int c = 0; c < 4; ++c) {
      float s = part[k][c];
      #pragma unroll
      for (int off = 32; off >= 1; off >>= 1) s += __shfl_xor(s, off, 64);
      part[k][c] = s;
    }
  if (lane == 0) {
    f4 v0 = {part[0][0],part[0][1],part[0][2],part[0][3]};
    f4 v1 = {part[1][0],part[1][1],part[1][2],part[1][3]};
    f4 v2 = {part[2][0],part[2][1],part[2][2],part[2][3]};
    f4 v3 = {part[3][0],part[3][1],part[3][2],part[3][3]};
    p0[n]=v0; p1[n]=v1; p2[n]=v2; p3[n]=v3;
  }
}

// ---------------- host launch ----------------
extern "C" void kernel_launch(void* const* d_in, const int* in_sizes, int n_in,
                              void* d_out, int out_size, void* d_ws, size_t ws_size,
                              hipStream_t stream) {
  const float* x   = (const float*)d_in[0];
  const int*   ei  = (const int*)d_in[1];
  const int*   src = ei;
  const int*   dst = ei + NE;
  const float* w   = (const float*)d_in[2];
  const float* W1  = (const float*)d_in[3];
  const float* b1  = (const float*)d_in[4];
  const float* W2  = (const float*)d_in[5];
  const float* b2  = (const float*)d_in[6];
  const float* W3  = (const float*)d_in[7];
  const float* b3  = (const float*)d_in[8];
  const float* g1w = (const float*)d_in[9];
  const float* g1b = (const float*)d_in[10];
  const float* g1a = (const float*)d_in[11];
  const float* g2w = (const float*)d_in[12];
  const float* g2b = (const float*)d_in[13];
  const float* g2a = (const float*)d_in[14];

  char* p = (char*)d_ws;
  auto alloc = [&](size_t bytes) -> void* {
    void* r = (void*)p;
    p += (bytes + 255) & ~(size_t)255;
    return r;
  };
  float* deg      = (float*)alloc(NN*4);
  int*   cnt      = (int*)  alloc(NN*4);
  int*   row_ptr  = (int*)  alloc((NN+1)*4);
  int*   cursor   = (int*)  alloc(NN*4);
  int*   btot     = (int*)  alloc(256*4);
  int*   boff     = (int*)  alloc(256*4);
  int*   csr_src  = (int*)  alloc((size_t)NE*4);
  float* csr_nrm  = (float*)alloc((size_t)NE*4);
  f4*    h1       = (f4*)   alloc((size_t)NN*16);
  f4*    h2       = (f4*)   alloc((size_t)NN*16);
  f4*    h3       = (f4*)   alloc((size_t)NN*16);
  f4*    p0       = (f4*)   alloc((size_t)NN*16);
  f4*    p1       = (f4*)   alloc((size_t)NN*16);
  f4*    p2       = (f4*)   alloc((size_t)NN*16);
  f4*    p3       = (f4*)   alloc((size_t)NN*16);
  f4*    t1       = (f4*)   alloc((size_t)NN*16);
  f4*    t2       = (f4*)   alloc((size_t)NN*16);
  float* stats    = (float*)alloc(1024*4);
  float* s1 = stats, *s2 = stats + 512;
  float* scb      = (float*)alloc(HD*4);
  float* shb      = (float*)alloc(HD*4);
  float* pS       = (float*)alloc((size_t)STATS_NB*HD*4);   // 1 MB (reused)
  float* pQ       = (float*)alloc((size_t)STATS_NB*HD*4);   // 1 MB
  u16*   W2T      = (u16*)  alloc((size_t)4*HD*HD*2);       // 2 MB
  // big buffers: 102.4 MB f32 + 2 x 51.2 MB bf16
  float* bigf     = (float*)alloc((size_t)NN*HD*4);
  u16*   bfA      = (u16*)  alloc((size_t)NN*HD*2);
  u16*   bfB      = (u16*)  alloc((size_t)NN*HD*2);

  const int TPB = 256;
  int gridE = (NE + TPB - 1)/TPB;
  int gridN = (NN + TPB - 1)/TPB;
  int gridNorm = (int)(((size_t)NN*HD/4 + 255)/256);
  int gridP = (NN + 3)/4;

  // CSR + norm
  hipMemsetAsync(deg, 0, NN*4, stream);
  hipMemsetAsync(cnt, 0, NN*4, stream);
  k_deg<<<gridE, TPB, 0, stream>>>(dst, w, deg, cnt);
  k_dinv<<<gridN, TPB, 0, stream>>>(deg);
  k_scanA<<<NBCHUNK, 256, 0, stream>>>(cnt, row_ptr, btot);
  k_scanB<<<1, 256, 0, stream>>>(btot, boff);
  k_scanC<<<NBCHUNK, 256, 0, stream>>>(row_ptr, boff);
  hipMemsetAsync(cursor, 0, NN*4, stream);
  k_fill<<<gridE, TPB, 0, stream>>>(src, dst, w, deg, row_ptr, cursor, csr_src, csr_nrm);
  k_w2t<<<(4*HD*HD + 255)/256, 256, 0, stream>>>(W2, W2T);

  // Layer 1
  k_prop4<<<gridN, TPB, 0, stream>>>(row_ptr, csr_src, csr_nrm, (const f4*)x, nullptr, nullptr, nullptr, h1);
  k_prop4<<<gridN, TPB, 0, stream>>>(row_ptr, csr_src, csr_nrm, h1, nullptr, nullptr, nullptr, h2);
  k_prop4<<<gridN, TPB, 0, stream>>>(row_ptr, csr_src, csr_nrm, h2, nullptr, nullptr, nullptr, h3);
  k_combine1<<<NN, 128, 0, stream>>>((const f4*)x, h1, h2, h3, W1, b1, bigf);

  // GraphNorm 1 -> bf16
  k_stats1<<<STATS_NB, 256, 0, stream>>>(bigf, pS, pQ);
  k_reduce<<<2, 256, 0, stream>>>(pS, pQ, STATS_NB, s1, s2);
  k_affine<<<2, 256, 0, stream>>>(s1, s2, g1w, g1b, g1a, scb, shb);
  k_norm_tobf<<<gridNorm, 256, 0, stream>>>(bigf, bfA, scb, shb);

  // Layer 2: A0=bfA, A1=prop(A0)=bfB -> GEMM1 writes C;
  //          A2=prop(A1)=bfA, A3=prop(A2)=bfB -> GEMM2 accumulates + bias+ELU+stats
  dim3 ggrid(GRIDM, HD/BN);
  k_prop512_bf<<<gridP, 256, 0, stream>>>(row_ptr, csr_src, csr_nrm, bfA, bfB);
  k_gemm2<0><<<ggrid, 256, 0, stream>>>(bfA, bfB, W2T, W2T + (size_t)HD*HD,
                                        bigf, nullptr, nullptr, nullptr, NN);
  k_prop512_bf<<<gridP, 256, 0, stream>>>(row_ptr, csr_src, csr_nrm, bfB, bfA);
  k_prop512_bf<<<gridP, 256, 0, stream>>>(row_ptr, csr_src, csr_nrm, bfA, bfB);
  k_gemm2<1><<<ggrid, 256, 0, stream>>>(bfA, bfB, W2T + 2*(size_t)HD*HD, W2T + 3*(size_t)HD*HD,
                                        bigf, b2, pS, pQ, NN);

  // GraphNorm 2 affine from GEMM-fused partials
  k_reduce<<<2, 256, 0, stream>>>(pS, pQ, GRIDM, s1, s2);
  k_affine<<<2, 256, 0, stream>>>(s1, s2, g2w, g2b, g2a, scb, shb);

  // Layer 3: fused-norm narrow linears, then Horner with width-4 propagations
  k_lin3<<<gridP, 256, 0, stream>>>(bigf, scb, shb, W3, p0, p1, p2, p3);
  k_prop4<<<gridN, TPB, 0, stream>>>(row_ptr, csr_src, csr_nrm, p3, nullptr, nullptr, nullptr, t1);
  k_prop4<<<gridN, TPB, 0, stream>>>(row_ptr, csr_src, csr_nrm, p2, t1, nullptr, nullptr, t2);
  k_prop4<<<gridN, TPB, 0, stream>>>(row_ptr, csr_src, csr_nrm, p1, t2, p0, b3, (f4*)d_out);
}

// Round 5
// 1159.064 us; speedup vs baseline: 2.1349x; 1.0753x over previous
//
#include <hip/hip_runtime.h>
#include <math.h>

// Problem constants
#define NN 50000      // nodes
#define NE 800000     // edges
#define HD 512        // hidden
#define GN_EPS 1e-5f
#define NBCHUNK 196   // ceil(NN/256) for scan
#define GRIDM 391     // ceil(NN/128) GEMM grid rows
#define STATS_NB 512  // combine1 stats partial blocks

typedef __attribute__((ext_vector_type(4))) float f4;
typedef __attribute__((ext_vector_type(4))) float f32x4;
typedef __attribute__((ext_vector_type(8))) short short8;
typedef unsigned short u16;
typedef __attribute__((ext_vector_type(4))) unsigned short us4;
typedef __attribute__((ext_vector_type(8))) unsigned short us8;

static __device__ __forceinline__ float elu1(float v){ return v > 0.f ? v : expm1f(v); }

static __device__ __forceinline__ float bf2f(u16 u){
  union { unsigned int i; float f; } v; v.i = ((unsigned int)u) << 16; return v.f;
}
static __device__ __forceinline__ u16 f2bf(float f){
  union { float f; unsigned int i; } v; v.f = f;
  unsigned int b = v.i;
  b += 0x7FFFu + ((b >> 16) & 1u);   // round-to-nearest-even
  return (u16)(b >> 16);
}

// st_16x32 LDS swizzle (m201): XOR byte-bit5 with byte-bit9; involution, keeps 16B align
static __device__ __forceinline__ int swz(int b){ return b ^ (((b >> 9) & 1) << 5); }

// ---------------- CSR build ----------------
__global__ void k_deg(const int* __restrict__ dst, const float* __restrict__ w,
                      float* __restrict__ deg, int* __restrict__ cnt) {
  int e = blockIdx.x*256 + threadIdx.x;
  if (e < NE) {
    int d = dst[e];
    atomicAdd(&deg[d], w[e]);
    atomicAdd(&cnt[d], 1);
  }
}

__global__ void k_dinv(float* __restrict__ deg) {
  int n = blockIdx.x*256 + threadIdx.x;
  if (n < NN) { float d = deg[n]; deg[n] = d > 0.f ? rsqrtf(d) : 0.f; }
}

// hierarchical scan: chunk-local inclusive -> chunk totals
__global__ void __launch_bounds__(256) k_scanA(const int* __restrict__ cnt,
                                               int* __restrict__ row_ptr,
                                               int* __restrict__ btot) {
  __shared__ int sh[256];
  int t = threadIdx.x, b = blockIdx.x;
  int i = b*256 + t;
  int v = (i < NN) ? cnt[i] : 0;
  sh[t] = v; __syncthreads();
  #pragma unroll
  for (int off = 1; off < 256; off <<= 1) {
    int x = (t >= off) ? sh[t-off] : 0;
    __syncthreads();
    sh[t] += x;
    __syncthreads();
  }
  if (i < NN) row_ptr[i+1] = sh[t];
  if (t == 255) btot[b] = sh[255];
}

__global__ void __launch_bounds__(256) k_scanB(const int* __restrict__ btot,
                                               int* __restrict__ boff) {
  __shared__ int sh[256];
  int t = threadIdx.x;
  int v = (t < NBCHUNK) ? btot[t] : 0;
  sh[t] = v; __syncthreads();
  #pragma unroll
  for (int off = 1; off < 256; off <<= 1) {
    int x = (t >= off) ? sh[t-off] : 0;
    __syncthreads();
    sh[t] += x;
    __syncthreads();
  }
  if (t < NBCHUNK) boff[t] = sh[t] - v;   // exclusive
}

__global__ void __launch_bounds__(256) k_scanC(int* __restrict__ row_ptr,
                                               const int* __restrict__ boff) {
  int t = threadIdx.x, b = blockIdx.x;
  int i = b*256 + t;
  if (i < NN) row_ptr[i+1] += boff[b];
  if (i == 0) row_ptr[0] = 0;
}

__global__ void k_fill(const int* __restrict__ src, const int* __restrict__ dst,
                       const float* __restrict__ w, const float* __restrict__ dinv,
                       const int* __restrict__ row_ptr, int* __restrict__ cursor,
                       int* __restrict__ csr_src, float* __restrict__ csr_norm) {
  int e = blockIdx.x*256 + threadIdx.x;
  if (e < NE) {
    int s = src[e], d = dst[e];
    int pos = atomicAdd(&cursor[d], 1);
    int idx = row_ptr[d] + pos;
    csr_src[idx] = s;
    csr_norm[idx] = dinv[s] * w[e] * dinv[d];
  }
}

// ---------------- width-4 propagation (layers 1 & 3), all f32 ----------------
__global__ void k_prop4(const int* __restrict__ row_ptr, const int* __restrict__ csr_src,
                        const float* __restrict__ csr_norm,
                        const f4* __restrict__ in1, const f4* __restrict__ in2,
                        const f4* __restrict__ base, const float* __restrict__ bias,
                        f4* __restrict__ out) {
  int n = blockIdx.x*256 + threadIdx.x;
  if (n >= NN) return;
  f4 acc = {0.f,0.f,0.f,0.f};
  int e0 = row_ptr[n], e1 = row_ptr[n+1];
  if (in2) {
    for (int e = e0; e < e1; ++e) {
      int s = csr_src[e]; float wv = csr_norm[e];
      acc += wv * (in1[s] + in2[s]);
    }
  } else {
    for (int e = e0; e < e1; ++e) {
      int s = csr_src[e]; float wv = csr_norm[e];
      acc += wv * in1[s];
    }
  }
  if (base) acc += base[n];
  if (bias) { acc[0]+=bias[0]; acc[1]+=bias[1]; acc[2]+=bias[2]; acc[3]+=bias[3]; }
  out[n] = acc;
}

// ---------------- width-512 propagation on bf16, one wave per node ----------------
__global__ void __launch_bounds__(256) k_prop512_bf(
    const int* __restrict__ row_ptr, const int* __restrict__ csr_src,
    const float* __restrict__ csr_norm,
    const u16* __restrict__ in, u16* __restrict__ out) {
  int wv = threadIdx.x >> 6;
  int l  = threadIdx.x & 63;
  int n = blockIdx.x*4 + wv;
  if (n >= NN) return;
  int e0 = row_ptr[n], e1 = row_ptr[n+1];
  float acc[8] = {0.f,0.f,0.f,0.f,0.f,0.f,0.f,0.f};
  const u16* basep = in + l*8;
  for (int e = e0; e < e1; ++e) {
    int s = csr_src[e]; float wn = csr_norm[e];
    us8 v = *reinterpret_cast<const us8*>(basep + (size_t)s*HD);
    #pragma unroll
    for (int q = 0; q < 8; ++q) acc[q] += wn * bf2f(v[q]);
  }
  us8 o;
  #pragma unroll
  for (int q = 0; q < 8; ++q) o[q] = f2bf(acc[q]);
  *reinterpret_cast<us8*>(out + (size_t)n*HD + l*8) = o;
}

// ---------------- layer-1 combine fused with stats: bf16 out + column partials ----------------
__global__ void __launch_bounds__(256) k_combine1s(
    const f4* __restrict__ x, const f4* __restrict__ h1, const f4* __restrict__ h2,
    const f4* __restrict__ h3, const float* __restrict__ W1, const float* __restrict__ b1,
    u16* __restrict__ act, float* __restrict__ pS, float* __restrict__ pQ) {
  __shared__ float sdS[HD], sdQ[HD];
  int t = threadIdx.x;
  int half = t >> 7;
  int c4 = (t & 127) * 4;
  f4 wcol[16];
  #pragma unroll
  for (int kf = 0; kf < 16; ++kf)
    wcol[kf] = *reinterpret_cast<const f4*>(W1 + (size_t)kf*HD + c4);
  f4 bv = *reinterpret_cast<const f4*>(b1 + c4);
  f4 s = {0.f,0.f,0.f,0.f}, qq = {0.f,0.f,0.f,0.f};
  for (int n = blockIdx.x*2 + half; n < NN; n += gridDim.x*2) {
    f4 hv0 = x[n], hv1 = h1[n], hv2 = h2[n], hv3 = h3[n];
    f4 acc = bv;
    #pragma unroll
    for (int f = 0; f < 4; ++f) acc += hv0[f] * wcol[f];
    #pragma unroll
    for (int f = 0; f < 4; ++f) acc += hv1[f] * wcol[4+f];
    #pragma unroll
    for (int f = 0; f < 4; ++f) acc += hv2[f] * wcol[8+f];
    #pragma unroll
    for (int f = 0; f < 4; ++f) acc += hv3[f] * wcol[12+f];
    us4 o;
    #pragma unroll
    for (int e = 0; e < 4; ++e) {
      float v = elu1(acc[e]);
      s[e] += v; qq[e] += v*v;
      o[e] = f2bf(v);
    }
    *reinterpret_cast<us4*>(act + (size_t)n*HD + c4) = o;
  }
  if (half) {
    *reinterpret_cast<f4*>(&sdS[c4]) = s;
    *reinterpret_cast<f4*>(&sdQ[c4]) = qq;
  }
  __syncthreads();
  if (!half) {
    f4 ts = *reinterpret_cast<f4*>(&sdS[c4]) + s;
    f4 tq = *reinterpret_cast<f4*>(&sdQ[c4]) + qq;
    *reinterpret_cast<f4*>(&pS[(size_t)blockIdx.x*HD + c4]) = ts;
    *reinterpret_cast<f4*>(&pQ[(size_t)blockIdx.x*HD + c4]) = tq;
  }
}

// ---------------- reduce partials [nb][512] -> s1,s2 ----------------
__global__ void __launch_bounds__(256) k_reduce(
    const float* __restrict__ pS, const float* __restrict__ pQ, int nb,
    float* __restrict__ s1, float* __restrict__ s2) {
  int c = blockIdx.x*256 + threadIdx.x;
  if (c >= HD) return;
  float a = 0.f, b = 0.f;
  for (int i = 0; i < nb; ++i) {
    a += pS[(size_t)i*HD + c];
    b += pQ[(size_t)i*HD + c];
  }
  s1[c] = a; s2[c] = b;
}

// ---------------- GraphNorm scale/shift precompute: v_norm = sc*v + sh ----------------
__global__ void k_affine(const float* __restrict__ s1, const float* __restrict__ s2,
                         const float* __restrict__ gw, const float* __restrict__ gb,
                         const float* __restrict__ ga,
                         float* __restrict__ sc, float* __restrict__ sh) {
  int c = blockIdx.x*256 + threadIdx.x;
  if (c >= HD) return;
  float mu = s1[c]*(1.f/NN);
  float a  = ga[c];
  float var = s2[c]*(1.f/NN) - 2.f*a*mu*mu + a*a*mu*mu;
  float inv = rsqrtf(var + GN_EPS);
  sc[c] = gw[c]*inv;
  sh[c] = gb[c] - gw[c]*inv*a*mu;
}

// ---------------- in-place bf16 normalize with precomputed sc/sh ----------------
__global__ void k_norm_ip(u16* __restrict__ buf, const float* __restrict__ sc,
                          const float* __restrict__ sh) {
  size_t i = (size_t)blockIdx.x*256 + threadIdx.x;
  size_t total = (size_t)NN*HD/8;
  if (i >= total) return;
  int c = (int)((i*8) % HD);
  us8 v = reinterpret_cast<us8*>(buf)[i];
  #pragma unroll
  for (int e = 0; e < 8; ++e) v[e] = f2bf(bf2f(v[e])*sc[c+e] + sh[c+e]);
  reinterpret_cast<us8*>(buf)[i] = v;
}

// ---------------- W2 -> bf16 transposed: Bt[k][out][in] = bf16(W2[k][in][out]) ----------------
__global__ void k_w2t(const float* __restrict__ W2, u16* __restrict__ Bt) {
  size_t idx = (size_t)blockIdx.x*256 + threadIdx.x;
  if (idx >= (size_t)4*HD*HD) return;
  int i = (int)(idx & 511);          // in  (fastest -> coalesced write)
  int o = (int)((idx >> 9) & 511);   // out
  int k = (int)(idx >> 18);
  Bt[idx] = f2bf(W2[((size_t)k*HD + i)*HD + o]);
}

// ---------------- MFMA bf16 dual-source GEMM (K=1024): C = A0@B0^T + A1@B1^T ----------------
// BK=64, 128B LDS rows + st_16x32 swizzle (write & read), XCD-bijective block remap.
// FINAL=1: C += ..., then v=elu(C+bias), write v, emit per-channel partial sums.
#define BM 128
#define BN 128
#define BKS 64
template<int FINAL>
__global__ void __launch_bounds__(256) k_gemm2(
    const u16* __restrict__ A0, const u16* __restrict__ A1,
    const u16* __restrict__ B0, const u16* __restrict__ B1,
    float* __restrict__ C, const float* __restrict__ bias,
    float* __restrict__ pS, float* __restrict__ pQ, int M) {
  __shared__ u16 As[BM*BKS];   // 16 KB, rows of 128B
  __shared__ u16 Bs[BN*BKS];   // 16 KB
  __shared__ float sdS[BN], sdQ[BN];
  int t = threadIdx.x;

  // XCD-bijective remap (m204), col-fastest within consecutive ids
  int nwg = gridDim.x;            // GRIDM*4
  int q = nwg >> 3, r = nwg & 7;
  int xcd = blockIdx.x & 7, sub = blockIdx.x >> 3;
  int nid = (xcd < r ? xcd*(q+1) : r*(q+1) + (xcd - r)*q) + sub;
  int bmi = nid >> 2;             // row-panel index (0..GRIDM-1)
  int bni = nid & 3;              // col-panel index (0..3)
  int bm = bmi * BM, bn = bni * BN;

  int w  = t >> 6;
  int l  = t & 63;
  int wr = (w >> 1) * 64;
  int wc = (w & 1) * 64;
  int lr = l & 15;
  int lq = l >> 4;

  if (FINAL && t < BN) { sdS[t] = 0.f; sdQ[t] = 0.f; }

  // staging map: 4 slots/thread; slot s -> row = s>>3, 16B-chunk c8 = s&7
  int aoff[4], boff[4], wb[4];
  #pragma unroll
  for (int p2 = 0; p2 < 4; ++p2) {
    int s = p2*256 + t;
    int row = s >> 3, c8 = s & 7;
    int ga = bm + row; if (ga >= M) ga = M - 1;
    aoff[p2] = ga*HD + c8*8;
    boff[p2] = (bn + row)*HD + c8*8;
    wb[p2] = swz(row*128 + c8*16);
  }

  f32x4 acc[4][4];
  #pragma unroll
  for (int i = 0; i < 4; ++i)
    #pragma unroll
    for (int j = 0; j < 4; ++j) acc[i][j] = (f32x4){0.f,0.f,0.f,0.f};

  us8 ra[4], rb[4];
  #pragma unroll
  for (int p2 = 0; p2 < 4; ++p2) {
    ra[p2] = *reinterpret_cast<const us8*>(A0 + aoff[p2]);
    rb[p2] = *reinterpret_cast<const us8*>(B0 + boff[p2]);
  }

  for (int k0 = 0; k0 < 2*HD; k0 += BKS) {
    __syncthreads();   // previous iteration's LDS reads complete
    #pragma unroll
    for (int p2 = 0; p2 < 4; ++p2) {
      *reinterpret_cast<us8*>((char*)As + wb[p2]) = ra[p2];
      *reinterpret_cast<us8*>((char*)Bs + wb[p2]) = rb[p2];
    }
    int k1 = k0 + BKS;
    if (k1 < 2*HD) {   // prefetch next K-tile (overlaps MFMA below)
      int off = k1 & (HD-1);
      const u16* Asrc = (k1 < HD) ? A0 : A1;
      const u16* Bsrc = (k1 < HD) ? B0 : B1;
      #pragma unroll
      for (int p2 = 0; p2 < 4; ++p2) {
        ra[p2] = *reinterpret_cast<const us8*>(Asrc + aoff[p2] + off);
        rb[p2] = *reinterpret_cast<const us8*>(Bsrc + boff[p2] + off);
      }
    }
    __syncthreads();   // tile ready
    #pragma unroll
    for (int ks = 0; ks < 2; ++ks) {
      short8 af[4], bfr[4];
      #pragma unroll
      for (int mi = 0; mi < 4; ++mi)
        af[mi] = *reinterpret_cast<const short8*>(
            (char*)As + swz((wr + mi*16 + lr)*128 + ks*64 + lq*16));
      #pragma unroll
      for (int ni = 0; ni < 4; ++ni)
        bfr[ni] = *reinterpret_cast<const short8*>(
            (char*)Bs + swz((wc + ni*16 + lr)*128 + ks*64 + lq*16));
      #pragma unroll
      for (int mi = 0; mi < 4; ++mi)
        #pragma unroll
        for (int ni = 0; ni < 4; ++ni)
          acc[mi][ni] = __builtin_amdgcn_mfma_f32_16x16x32_bf16(af[mi], bfr[ni], acc[mi][ni], 0, 0, 0);
    }
  }

  if (!FINAL) {
    #pragma unroll
    for (int mi = 0; mi < 4; ++mi)
      #pragma unroll
      for (int ni = 0; ni < 4; ++ni)
        #pragma unroll
        for (int rr = 0; rr < 4; ++rr) {
          int gm = bm + wr + mi*16 + lq*4 + rr;
          int gn = bn + wc + ni*16 + lr;
          if (gm < M) C[(size_t)gm*HD + gn] = acc[mi][ni][rr];
        }
  } else {
    float psum[4] = {0.f,0.f,0.f,0.f}, qsum[4] = {0.f,0.f,0.f,0.f};
    #pragma unroll
    for (int ni = 0; ni < 4; ++ni) {
      int gn = bn + wc + ni*16 + lr;
      float bgn = bias[gn];
      #pragma unroll
      for (int mi = 0; mi < 4; ++mi)
        #pragma unroll
        for (int rr = 0; rr < 4; ++rr) {
          int gm = bm + wr + mi*16 + lq*4 + rr;
          if (gm < M) {
            float* cp = &C[(size_t)gm*HD + gn];
            float v = elu1(*cp + acc[mi][ni][rr] + bgn);
            *cp = v;
            psum[ni] += v; qsum[ni] += v*v;
          }
        }
    }
    #pragma unroll
    for (int ni = 0; ni < 4; ++ni) {
      psum[ni] += __shfl_xor(psum[ni], 16, 64);
      psum[ni] += __shfl_xor(psum[ni], 32, 64);
      qsum[ni] += __shfl_xor(qsum[ni], 16, 64);
      qsum[ni] += __shfl_xor(qsum[ni], 32, 64);
    }
    if (lq == 0) {
      #pragma unroll
      for (int ni = 0; ni < 4; ++ni) {
        atomicAdd(&sdS[wc + ni*16 + lr], psum[ni]);   // exactly 2 contribs/slot
        atomicAdd(&sdQ[wc + ni*16 + lr], qsum[ni]);
      }
    }
    __syncthreads();
    if (t < BN) {
      pS[(size_t)bmi*HD + bn + t] = sdS[t];
      pQ[(size_t)bmi*HD + bn + t] = sdQ[t];
    }
  }
}

// ---------------- layer-3 linears with fused GraphNorm affine ----------------
__global__ void __launch_bounds__(256) k_lin3(
    const float* __restrict__ act, const float* __restrict__ sc, const float* __restrict__ sh,
    const float* __restrict__ W3,
    f4* __restrict__ p0, f4* __restrict__ p1, f4* __restrict__ p2, f4* __restrict__ p3) {
  int wave = threadIdx.x / 64;
  int lane = threadIdx.x % 64;
  int n = blockIdx.x*4 + wave;
  if (n >= NN) return;
  float part[4][4] = {};
  #pragma unroll
  for (int jj = 0; jj < 8; ++jj) {
    int j = lane + jj*64;
    float v = sc[j]*act[(size_t)n*HD + j] + sh[j];
    #pragma unroll
    for (int k = 0; k < 4; ++k) {
      f4 wv = *reinterpret_cast<const f4*>(W3 + ((size_t)k*HD + j)*4);
      #pragma unroll
      for (int c = 0; c < 4; ++c) part[k][c] += v * wv[c];
    }
  }
  #pragma unroll
  for (int k = 0; k < 4; ++k)
    #pragma unroll
    for (int c = 0; c < 4; ++c) {
      float s = part[k][c];
      #pragma unroll
      for (int off = 32; off >= 1; off >>= 1) s += __shfl_xor(s, off, 64);
      part[k][c] = s;
    }
  if (lane == 0) {
    f4 v0 = {part[0][0],part[0][1],part[0][2],part[0][3]};
    f4 v1 = {part[1][0],part[1][1],part[1][2],part[1][3]};
    f4 v2 = {part[2][0],part[2][1],part[2][2],part[2][3]};
    f4 v3 = {part[3][0],part[3][1],part[3][2],part[3][3]};
    p0[n]=v0; p1[n]=v1; p2[n]=v2; p3[n]=v3;
  }
}

// ---------------- host launch ----------------
extern "C" void kernel_launch(void* const* d_in, const int* in_sizes, int n_in,
                              void* d_out, int out_size, void* d_ws, size_t ws_size,
                              hipStream_t stream) {
  const float* x   = (const float*)d_in[0];
  const int*   ei  = (const int*)d_in[1];
  const int*   src = ei;
  const int*   dst = ei + NE;
  const float* w   = (const float*)d_in[2];
  const float* W1  = (const float*)d_in[3];
  const float* b1  = (const float*)d_in[4];
  const float* W2  = (const float*)d_in[5];
  const float* b2  = (const float*)d_in[6];
  const float* W3  = (const float*)d_in[7];
  const float* b3  = (const float*)d_in[8];
  const float* g1w = (const float*)d_in[9];
  const float* g1b = (const float*)d_in[10];
  const float* g1a = (const float*)d_in[11];
  const float* g2w = (const float*)d_in[12];
  const float* g2b = (const float*)d_in[13];
  const float* g2a = (const float*)d_in[14];

  char* p = (char*)d_ws;
  auto alloc = [&](size_t bytes) -> void* {
    void* r = (void*)p;
    p += (bytes + 255) & ~(size_t)255;
    return r;
  };
  float* deg      = (float*)alloc(NN*4);
  int*   cnt      = (int*)  alloc(NN*4);
  int*   row_ptr  = (int*)  alloc((NN+1)*4);
  int*   cursor   = (int*)  alloc(NN*4);
  int*   btot     = (int*)  alloc(256*4);
  int*   boff     = (int*)  alloc(256*4);
  int*   csr_src  = (int*)  alloc((size_t)NE*4);
  float* csr_nrm  = (float*)alloc((size_t)NE*4);
  f4*    h1       = (f4*)   alloc((size_t)NN*16);
  f4*    h2       = (f4*)   alloc((size_t)NN*16);
  f4*    h3       = (f4*)   alloc((size_t)NN*16);
  f4*    p0       = (f4*)   alloc((size_t)NN*16);
  f4*    p1       = (f4*)   alloc((size_t)NN*16);
  f4*    p2       = (f4*)   alloc((size_t)NN*16);
  f4*    p3       = (f4*)   alloc((size_t)NN*16);
  f4*    t1       = (f4*)   alloc((size_t)NN*16);
  f4*    t2       = (f4*)   alloc((size_t)NN*16);
  float* stats    = (float*)alloc(1024*4);
  float* s1 = stats, *s2 = stats + 512;
  float* scb      = (float*)alloc(HD*4);
  float* shb      = (float*)alloc(HD*4);
  float* pS       = (float*)alloc((size_t)STATS_NB*HD*4);   // 1 MB
  float* pQ       = (float*)alloc((size_t)STATS_NB*HD*4);   // 1 MB
  u16*   W2T      = (u16*)  alloc((size_t)4*HD*HD*2);       // 2 MB
  // big buffers: 102.4 MB f32 + 2 x 51.2 MB bf16  (~222 MB total)
  float* bigf     = (float*)alloc((size_t)NN*HD*4);
  u16*   bfA      = (u16*)  alloc((size_t)NN*HD*2);
  u16*   bfB      = (u16*)  alloc((size_t)NN*HD*2);

  const int TPB = 256;
  int gridE = (NE + TPB - 1)/TPB;
  int gridN = (NN + TPB - 1)/TPB;
  int gridIp = (int)(((size_t)NN*HD/8 + 255)/256);
  int gridP = (NN + 3)/4;

  // CSR + norm
  hipMemsetAsync(deg, 0, NN*4, stream);
  hipMemsetAsync(cnt, 0, NN*4, stream);
  k_deg<<<gridE, TPB, 0, stream>>>(dst, w, deg, cnt);
  k_dinv<<<gridN, TPB, 0, stream>>>(deg);
  k_scanA<<<NBCHUNK, 256, 0, stream>>>(cnt, row_ptr, btot);
  k_scanB<<<1, 256, 0, stream>>>(btot, boff);
  k_scanC<<<NBCHUNK, 256, 0, stream>>>(row_ptr, boff);
  hipMemsetAsync(cursor, 0, NN*4, stream);
  k_fill<<<gridE, TPB, 0, stream>>>(src, dst, w, deg, row_ptr, cursor, csr_src, csr_nrm);
  k_w2t<<<(4*HD*HD + 255)/256, 256, 0, stream>>>(W2, W2T);

  // Layer 1: hops, then fused combine+ELU+stats -> bf16 act (pre-norm) in bfA
  k_prop4<<<gridN, TPB, 0, stream>>>(row_ptr, csr_src, csr_nrm, (const f4*)x, nullptr, nullptr, nullptr, h1);
  k_prop4<<<gridN, TPB, 0, stream>>>(row_ptr, csr_src, csr_nrm, h1, nullptr, nullptr, nullptr, h2);
  k_prop4<<<gridN, TPB, 0, stream>>>(row_ptr, csr_src, csr_nrm, h2, nullptr, nullptr, nullptr, h3);
  k_combine1s<<<STATS_NB, 256, 0, stream>>>((const f4*)x, h1, h2, h3, W1, b1, bfA, pS, pQ);
  k_reduce<<<2, 256, 0, stream>>>(pS, pQ, STATS_NB, s1, s2);
  k_affine<<<2, 256, 0, stream>>>(s1, s2, g1w, g1b, g1a, scb, shb);
  k_norm_ip<<<gridIp, 256, 0, stream>>>(bfA, scb, shb);

  // Layer 2: A0=bfA, A1=prop(A0)=bfB -> GEMM1 writes C;
  //          A2=prop(A1)=bfA, A3=prop(A2)=bfB -> GEMM2 accumulates + bias+ELU+stats
  k_prop512_bf<<<gridP, 256, 0, stream>>>(row_ptr, csr_src, csr_nrm, bfA, bfB);
  k_gemm2<0><<<GRIDM*4, 256, 0, stream>>>(bfA, bfB, W2T, W2T + (size_t)HD*HD,
                                          bigf, nullptr, nullptr, nullptr, NN);
  k_prop512_bf<<<gridP, 256, 0, stream>>>(row_ptr, csr_src, csr_nrm, bfB, bfA);
  k_prop512_bf<<<gridP, 256, 0, stream>>>(row_ptr, csr_src, csr_nrm, bfA, bfB);
  k_gemm2<1><<<GRIDM*4, 256, 0, stream>>>(bfA, bfB, W2T + 2*(size_t)HD*HD, W2T + 3*(size_t)HD*HD,
                                          bigf, b2, pS, pQ, NN);

  // GraphNorm 2 affine from GEMM-fused partials
  k_reduce<<<2, 256, 0, stream>>>(pS, pQ, GRIDM, s1, s2);
  k_affine<<<2, 256, 0, stream>>>(s1, s2, g2w, g2b, g2a, scb, shb);

  // Layer 3: fused-norm narrow linears, then Horner with width-4 propagations
  k_lin3<<<gridP, 256, 0, stream>>>(bigf, scb, shb, W3, p0, p1, p2, p3);
  k_prop4<<<gridN, TPB, 0, stream>>>(row_ptr, csr_src, csr_nrm, p3, nullptr, nullptr, nullptr, t1);
  k_prop4<<<gridN, TPB, 0, stream>>>(row_ptr, csr_src, csr_nrm, p2, t1, nullptr, nullptr, t2);
  k_prop4<<<gridN, TPB, 0, stream>>>(row_ptr, csr_src, csr_nrm, p1, t2, p0, b3, (f4*)d_out);
}

// Round 6
// 1135.011 us; speedup vs baseline: 2.1802x; 1.0212x over previous
//
#include <hip/hip_runtime.h>
#include <math.h>

// Problem constants
#define NN 50000      // nodes
#define NE 800000     // edges
#define HD 512        // hidden
#define GN_EPS 1e-5f
#define NBCHUNK 196   // ceil(NN/256) for scan
#define GRIDM 391     // ceil(NN/128) GEMM grid rows
#define STATS_NB 512  // combine1 stats partial blocks

typedef __attribute__((ext_vector_type(4))) float f4;
typedef __attribute__((ext_vector_type(4))) float f32x4;
typedef __attribute__((ext_vector_type(8))) short short8;
typedef unsigned short u16;
typedef __attribute__((ext_vector_type(4))) unsigned short us4;
typedef __attribute__((ext_vector_type(8))) unsigned short us8;

static __device__ __forceinline__ float elu1(float v){ return v > 0.f ? v : expm1f(v); }

static __device__ __forceinline__ float bf2f(u16 u){
  union { unsigned int i; float f; } v; v.i = ((unsigned int)u) << 16; return v.f;
}
static __device__ __forceinline__ u16 f2bf(float f){
  union { float f; unsigned int i; } v; v.f = f;
  unsigned int b = v.i;
  b += 0x7FFFu + ((b >> 16) & 1u);   // round-to-nearest-even
  return (u16)(b >> 16);
}

// LDS address for [row][128B] tiles: XOR the 16B-slot index with (row&7).
// 16 lanes reading 16 consecutive rows at one slot then span all 32 banks (2-way = free).
static __device__ __forceinline__ int lds_addr(int row, int chunkByte){
  return row*128 + (chunkByte ^ ((row & 7) << 4));
}

// ---------------- CSR build ----------------
__global__ void k_deg(const int* __restrict__ dst, const float* __restrict__ w,
                      float* __restrict__ deg, int* __restrict__ cnt) {
  int e = blockIdx.x*256 + threadIdx.x;
  if (e < NE) {
    int d = dst[e];
    atomicAdd(&deg[d], w[e]);
    atomicAdd(&cnt[d], 1);
  }
}

__global__ void k_dinv(float* __restrict__ deg) {
  int n = blockIdx.x*256 + threadIdx.x;
  if (n < NN) { float d = deg[n]; deg[n] = d > 0.f ? rsqrtf(d) : 0.f; }
}

// hierarchical scan: chunk-local inclusive -> chunk totals
__global__ void __launch_bounds__(256) k_scanA(const int* __restrict__ cnt,
                                               int* __restrict__ row_ptr,
                                               int* __restrict__ btot) {
  __shared__ int sh[256];
  int t = threadIdx.x, b = blockIdx.x;
  int i = b*256 + t;
  int v = (i < NN) ? cnt[i] : 0;
  sh[t] = v; __syncthreads();
  #pragma unroll
  for (int off = 1; off < 256; off <<= 1) {
    int x = (t >= off) ? sh[t-off] : 0;
    __syncthreads();
    sh[t] += x;
    __syncthreads();
  }
  if (i < NN) row_ptr[i+1] = sh[t];
  if (t == 255) btot[b] = sh[255];
}

__global__ void __launch_bounds__(256) k_scanB(const int* __restrict__ btot,
                                               int* __restrict__ boff) {
  __shared__ int sh[256];
  int t = threadIdx.x;
  int v = (t < NBCHUNK) ? btot[t] : 0;
  sh[t] = v; __syncthreads();
  #pragma unroll
  for (int off = 1; off < 256; off <<= 1) {
    int x = (t >= off) ? sh[t-off] : 0;
    __syncthreads();
    sh[t] += x;
    __syncthreads();
  }
  if (t < NBCHUNK) boff[t] = sh[t] - v;   // exclusive
}

__global__ void __launch_bounds__(256) k_scanC(int* __restrict__ row_ptr,
                                               const int* __restrict__ boff) {
  int t = threadIdx.x, b = blockIdx.x;
  int i = b*256 + t;
  if (i < NN) row_ptr[i+1] += boff[b];
  if (i == 0) row_ptr[0] = 0;
}

__global__ void k_fill(const int* __restrict__ src, const int* __restrict__ dst,
                       const float* __restrict__ w, const float* __restrict__ dinv,
                       const int* __restrict__ row_ptr, int* __restrict__ cursor,
                       int* __restrict__ csr_src, float* __restrict__ csr_norm) {
  int e = blockIdx.x*256 + threadIdx.x;
  if (e < NE) {
    int s = src[e], d = dst[e];
    int pos = atomicAdd(&cursor[d], 1);
    int idx = row_ptr[d] + pos;
    csr_src[idx] = s;
    csr_norm[idx] = dinv[s] * w[e] * dinv[d];
  }
}

// ---------------- width-4 propagation (layers 1 & 3), all f32 ----------------
__global__ void k_prop4(const int* __restrict__ row_ptr, const int* __restrict__ csr_src,
                        const float* __restrict__ csr_norm,
                        const f4* __restrict__ in1, const f4* __restrict__ in2,
                        const f4* __restrict__ base, const float* __restrict__ bias,
                        f4* __restrict__ out) {
  int n = blockIdx.x*256 + threadIdx.x;
  if (n >= NN) return;
  f4 acc = {0.f,0.f,0.f,0.f};
  int e0 = row_ptr[n], e1 = row_ptr[n+1];
  if (in2) {
    for (int e = e0; e < e1; ++e) {
      int s = csr_src[e]; float wv = csr_norm[e];
      acc += wv * (in1[s] + in2[s]);
    }
  } else {
    for (int e = e0; e < e1; ++e) {
      int s = csr_src[e]; float wv = csr_norm[e];
      acc += wv * in1[s];
    }
  }
  if (base) acc += base[n];
  if (bias) { acc[0]+=bias[0]; acc[1]+=bias[1]; acc[2]+=bias[2]; acc[3]+=bias[3]; }
  out[n] = acc;
}

// ---------------- width-512 propagation on bf16, one wave per node ----------------
__global__ void __launch_bounds__(256) k_prop512_bf(
    const int* __restrict__ row_ptr, const int* __restrict__ csr_src,
    const float* __restrict__ csr_norm,
    const u16* __restrict__ in, u16* __restrict__ out) {
  int wv = threadIdx.x >> 6;
  int l  = threadIdx.x & 63;
  int n = blockIdx.x*4 + wv;
  if (n >= NN) return;
  int e0 = row_ptr[n], e1 = row_ptr[n+1];
  float acc[8] = {0.f,0.f,0.f,0.f,0.f,0.f,0.f,0.f};
  const u16* basep = in + l*8;
  for (int e = e0; e < e1; ++e) {
    int s = csr_src[e]; float wn = csr_norm[e];
    us8 v = *reinterpret_cast<const us8*>(basep + (size_t)s*HD);
    #pragma unroll
    for (int q = 0; q < 8; ++q) acc[q] += wn * bf2f(v[q]);
  }
  us8 o;
  #pragma unroll
  for (int q = 0; q < 8; ++q) o[q] = f2bf(acc[q]);
  *reinterpret_cast<us8*>(out + (size_t)n*HD + l*8) = o;
}

// ---------------- layer-1 combine fused with stats: bf16 out + column partials ----------------
__global__ void __launch_bounds__(256) k_combine1s(
    const f4* __restrict__ x, const f4* __restrict__ h1, const f4* __restrict__ h2,
    const f4* __restrict__ h3, const float* __restrict__ W1, const float* __restrict__ b1,
    u16* __restrict__ act, float* __restrict__ pS, float* __restrict__ pQ) {
  __shared__ float sdS[HD], sdQ[HD];
  int t = threadIdx.x;
  int half = t >> 7;
  int c4 = (t & 127) * 4;
  f4 wcol[16];
  #pragma unroll
  for (int kf = 0; kf < 16; ++kf)
    wcol[kf] = *reinterpret_cast<const f4*>(W1 + (size_t)kf*HD + c4);
  f4 bv = *reinterpret_cast<const f4*>(b1 + c4);
  f4 s = {0.f,0.f,0.f,0.f}, qq = {0.f,0.f,0.f,0.f};
  for (int n = blockIdx.x*2 + half; n < NN; n += gridDim.x*2) {
    f4 hv0 = x[n], hv1 = h1[n], hv2 = h2[n], hv3 = h3[n];
    f4 acc = bv;
    #pragma unroll
    for (int f = 0; f < 4; ++f) acc += hv0[f] * wcol[f];
    #pragma unroll
    for (int f = 0; f < 4; ++f) acc += hv1[f] * wcol[4+f];
    #pragma unroll
    for (int f = 0; f < 4; ++f) acc += hv2[f] * wcol[8+f];
    #pragma unroll
    for (int f = 0; f < 4; ++f) acc += hv3[f] * wcol[12+f];
    us4 o;
    #pragma unroll
    for (int e = 0; e < 4; ++e) {
      float v = elu1(acc[e]);
      s[e] += v; qq[e] += v*v;
      o[e] = f2bf(v);
    }
    *reinterpret_cast<us4*>(act + (size_t)n*HD + c4) = o;
  }
  if (half) {
    *reinterpret_cast<f4*>(&sdS[c4]) = s;
    *reinterpret_cast<f4*>(&sdQ[c4]) = qq;
  }
  __syncthreads();
  if (!half) {
    f4 ts = *reinterpret_cast<f4*>(&sdS[c4]) + s;
    f4 tq = *reinterpret_cast<f4*>(&sdQ[c4]) + qq;
    *reinterpret_cast<f4*>(&pS[(size_t)blockIdx.x*HD + c4]) = ts;
    *reinterpret_cast<f4*>(&pQ[(size_t)blockIdx.x*HD + c4]) = tq;
  }
}

// ---------------- reduce partials [nb][512] -> s1,s2 ----------------
__global__ void __launch_bounds__(256) k_reduce(
    const float* __restrict__ pS, const float* __restrict__ pQ, int nb,
    float* __restrict__ s1, float* __restrict__ s2) {
  int c = blockIdx.x*256 + threadIdx.x;
  if (c >= HD) return;
  float a = 0.f, b = 0.f;
  for (int i = 0; i < nb; ++i) {
    a += pS[(size_t)i*HD + c];
    b += pQ[(size_t)i*HD + c];
  }
  s1[c] = a; s2[c] = b;
}

// ---------------- GraphNorm scale/shift precompute: v_norm = sc*v + sh ----------------
__global__ void k_affine(const float* __restrict__ s1, const float* __restrict__ s2,
                         const float* __restrict__ gw, const float* __restrict__ gb,
                         const float* __restrict__ ga,
                         float* __restrict__ sc, float* __restrict__ sh) {
  int c = blockIdx.x*256 + threadIdx.x;
  if (c >= HD) return;
  float mu = s1[c]*(1.f/NN);
  float a  = ga[c];
  float var = s2[c]*(1.f/NN) - 2.f*a*mu*mu + a*a*mu*mu;
  float inv = rsqrtf(var + GN_EPS);
  sc[c] = gw[c]*inv;
  sh[c] = gb[c] - gw[c]*inv*a*mu;
}

// ---------------- in-place bf16 normalize with precomputed sc/sh ----------------
__global__ void k_norm_ip(u16* __restrict__ buf, const float* __restrict__ sc,
                          const float* __restrict__ sh) {
  size_t i = (size_t)blockIdx.x*256 + threadIdx.x;
  size_t total = (size_t)NN*HD/8;
  if (i >= total) return;
  int c = (int)((i*8) % HD);
  us8 v = reinterpret_cast<us8*>(buf)[i];
  #pragma unroll
  for (int e = 0; e < 8; ++e) v[e] = f2bf(bf2f(v[e])*sc[c+e] + sh[c+e]);
  reinterpret_cast<us8*>(buf)[i] = v;
}

// ---------------- W2 -> bf16 transposed: Bt[k][out][in] = bf16(W2[k][in][out]) ----------------
__global__ void k_w2t(const float* __restrict__ W2, u16* __restrict__ Bt) {
  size_t idx = (size_t)blockIdx.x*256 + threadIdx.x;
  if (idx >= (size_t)4*HD*HD) return;
  int i = (int)(idx & 511);          // in  (fastest -> coalesced write)
  int o = (int)((idx >> 9) & 511);   // out
  int k = (int)(idx >> 18);
  Bt[idx] = f2bf(W2[((size_t)k*HD + i)*HD + o]);
}

// ---------------- MFMA bf16 dual-source GEMM (K=1024): Cbf (+)= A0@B0^T + A1@B1^T ----------------
// BK=64, 128B LDS rows, conflict-free (row&7)-slot XOR swizzle, XCD-bijective remap.
// FINAL=0: Cbf = bf16(partial).  FINAL=1: v=elu(bf2f(Cbf)+acc+bias); Cbf=v; per-channel stats.
#define BM 128
#define BN 128
#define BKS 64
template<int FINAL>
__global__ void __launch_bounds__(256) k_gemm2(
    const u16* __restrict__ A0, const u16* __restrict__ A1,
    const u16* __restrict__ B0, const u16* __restrict__ B1,
    u16* __restrict__ Cbf, const float* __restrict__ bias,
    float* __restrict__ pS, float* __restrict__ pQ, int M) {
  __shared__ u16 As[BM*BKS];   // 16 KB, rows of 128B
  __shared__ u16 Bs[BN*BKS];   // 16 KB
  __shared__ float sdS[BN], sdQ[BN];
  int t = threadIdx.x;

  // XCD-bijective remap (m204), col-fastest within consecutive ids
  int nwg = gridDim.x;            // GRIDM*4
  int q = nwg >> 3, r = nwg & 7;
  int xcd = blockIdx.x & 7, sub = blockIdx.x >> 3;
  int nid = (xcd < r ? xcd*(q+1) : r*(q+1) + (xcd - r)*q) + sub;
  int bmi = nid >> 2;             // row-panel index (0..GRIDM-1)
  int bni = nid & 3;              // col-panel index (0..3)
  int bm = bmi * BM, bn = bni * BN;

  int w  = t >> 6;
  int l  = t & 63;
  int wr = (w >> 1) * 64;
  int wc = (w & 1) * 64;
  int lr = l & 15;
  int lq = l >> 4;

  if (FINAL && t < BN) { sdS[t] = 0.f; sdQ[t] = 0.f; }

  // staging map: 4 slots/thread; slot s -> row = s>>3, 16B-chunk c8 = s&7
  int aoff[4], boff[4], wb[4];
  #pragma unroll
  for (int p2 = 0; p2 < 4; ++p2) {
    int s = p2*256 + t;
    int row = s >> 3, c8 = s & 7;
    int ga = bm + row; if (ga >= M) ga = M - 1;
    aoff[p2] = ga*HD + c8*8;
    boff[p2] = (bn + row)*HD + c8*8;
    wb[p2] = lds_addr(row, c8*16);
  }

  f32x4 acc[4][4];
  #pragma unroll
  for (int i = 0; i < 4; ++i)
    #pragma unroll
    for (int j = 0; j < 4; ++j) acc[i][j] = (f32x4){0.f,0.f,0.f,0.f};

  us8 ra[4], rb[4];
  #pragma unroll
  for (int p2 = 0; p2 < 4; ++p2) {
    ra[p2] = *reinterpret_cast<const us8*>(A0 + aoff[p2]);
    rb[p2] = *reinterpret_cast<const us8*>(B0 + boff[p2]);
  }

  for (int k0 = 0; k0 < 2*HD; k0 += BKS) {
    __syncthreads();   // previous iteration's LDS reads complete
    #pragma unroll
    for (int p2 = 0; p2 < 4; ++p2) {
      *reinterpret_cast<us8*>((char*)As + wb[p2]) = ra[p2];
      *reinterpret_cast<us8*>((char*)Bs + wb[p2]) = rb[p2];
    }
    int k1 = k0 + BKS;
    if (k1 < 2*HD) {   // prefetch next K-tile (overlaps MFMA below)
      int off = k1 & (HD-1);
      const u16* Asrc = (k1 < HD) ? A0 : A1;
      const u16* Bsrc = (k1 < HD) ? B0 : B1;
      #pragma unroll
      for (int p2 = 0; p2 < 4; ++p2) {
        ra[p2] = *reinterpret_cast<const us8*>(Asrc + aoff[p2] + off);
        rb[p2] = *reinterpret_cast<const us8*>(Bsrc + boff[p2] + off);
      }
    }
    __syncthreads();   // tile ready
    #pragma unroll
    for (int ks = 0; ks < 2; ++ks) {
      short8 af[4], bfr[4];
      #pragma unroll
      for (int mi = 0; mi < 4; ++mi)
        af[mi] = *reinterpret_cast<const short8*>(
            (char*)As + lds_addr(wr + mi*16 + lr, ks*64 + lq*16));
      #pragma unroll
      for (int ni = 0; ni < 4; ++ni)
        bfr[ni] = *reinterpret_cast<const short8*>(
            (char*)Bs + lds_addr(wc + ni*16 + lr, ks*64 + lq*16));
      #pragma unroll
      for (int mi = 0; mi < 4; ++mi)
        #pragma unroll
        for (int ni = 0; ni < 4; ++ni)
          acc[mi][ni] = __builtin_amdgcn_mfma_f32_16x16x32_bf16(af[mi], bfr[ni], acc[mi][ni], 0, 0, 0);
    }
  }

  if (!FINAL) {
    #pragma unroll
    for (int mi = 0; mi < 4; ++mi)
      #pragma unroll
      for (int ni = 0; ni < 4; ++ni)
        #pragma unroll
        for (int rr = 0; rr < 4; ++rr) {
          int gm = bm + wr + mi*16 + lq*4 + rr;
          int gn = bn + wc + ni*16 + lr;
          if (gm < M) Cbf[(size_t)gm*HD + gn] = f2bf(acc[mi][ni][rr]);
        }
  } else {
    float psum[4] = {0.f,0.f,0.f,0.f}, qsum[4] = {0.f,0.f,0.f,0.f};
    #pragma unroll
    for (int ni = 0; ni < 4; ++ni) {
      int gn = bn + wc + ni*16 + lr;
      float bgn = bias[gn];
      #pragma unroll
      for (int mi = 0; mi < 4; ++mi)
        #pragma unroll
        for (int rr = 0; rr < 4; ++rr) {
          int gm = bm + wr + mi*16 + lq*4 + rr;
          if (gm < M) {
            u16* cp = &Cbf[(size_t)gm*HD + gn];
            float v = elu1(bf2f(*cp) + acc[mi][ni][rr] + bgn);
            *cp = f2bf(v);
            psum[ni] += v; qsum[ni] += v*v;
          }
        }
    }
    #pragma unroll
    for (int ni = 0; ni < 4; ++ni) {
      psum[ni] += __shfl_xor(psum[ni], 16, 64);
      psum[ni] += __shfl_xor(psum[ni], 32, 64);
      qsum[ni] += __shfl_xor(qsum[ni], 16, 64);
      qsum[ni] += __shfl_xor(qsum[ni], 32, 64);
    }
    if (lq == 0) {
      #pragma unroll
      for (int ni = 0; ni < 4; ++ni) {
        atomicAdd(&sdS[wc + ni*16 + lr], psum[ni]);   // exactly 2 contribs/slot
        atomicAdd(&sdQ[wc + ni*16 + lr], qsum[ni]);
      }
    }
    __syncthreads();
    if (t < BN) {
      pS[(size_t)bmi*HD + bn + t] = sdS[t];
      pQ[(size_t)bmi*HD + bn + t] = sdQ[t];
    }
  }
}

// ---------------- layer-3 linears (bf16 act) with fused GraphNorm affine ----------------
__global__ void __launch_bounds__(256) k_lin3(
    const u16* __restrict__ act, const float* __restrict__ sc, const float* __restrict__ sh,
    const float* __restrict__ W3,
    f4* __restrict__ p0, f4* __restrict__ p1, f4* __restrict__ p2, f4* __restrict__ p3) {
  int wave = threadIdx.x / 64;
  int lane = threadIdx.x % 64;
  int n = blockIdx.x*4 + wave;
  if (n >= NN) return;
  float part[4][4] = {};
  #pragma unroll
  for (int jj = 0; jj < 8; ++jj) {
    int j = lane + jj*64;
    float v = sc[j]*bf2f(act[(size_t)n*HD + j]) + sh[j];
    #pragma unroll
    for (int k = 0; k < 4; ++k) {
      f4 wv = *reinterpret_cast<const f4*>(W3 + ((size_t)k*HD + j)*4);
      #pragma unroll
      for (int c = 0; c < 4; ++c) part[k][c] += v * wv[c];
    }
  }
  #pragma unroll
  for (int k = 0; k < 4; ++k)
    #pragma unroll
    for (int c = 0; c < 4; ++c) {
      float s = part[k][c];
      #pragma unroll
      for (int off = 32; off >= 1; off >>= 1) s += __shfl_xor(s, off, 64);
      part[k][c] = s;
    }
  if (lane == 0) {
    f4 v0 = {part[0][0],part[0][1],part[0][2],part[0][3]};
    f4 v1 = {part[1][0],part[1][1],part[1][2],part[1][3]};
    f4 v2 = {part[2][0],part[2][1],part[2][2],part[2][3]};
    f4 v3 = {part[3][0],part[3][1],part[3][2],part[3][3]};
    p0[n]=v0; p1[n]=v1; p2[n]=v2; p3[n]=v3;
  }
}

// ---------------- host launch ----------------
extern "C" void kernel_launch(void* const* d_in, const int* in_sizes, int n_in,
                              void* d_out, int out_size, void* d_ws, size_t ws_size,
                              hipStream_t stream) {
  const float* x   = (const float*)d_in[0];
  const int*   ei  = (const int*)d_in[1];
  const int*   src = ei;
  const int*   dst = ei + NE;
  const float* w   = (const float*)d_in[2];
  const float* W1  = (const float*)d_in[3];
  const float* b1  = (const float*)d_in[4];
  const float* W2  = (const float*)d_in[5];
  const float* b2  = (const float*)d_in[6];
  const float* W3  = (const float*)d_in[7];
  const float* b3  = (const float*)d_in[8];
  const float* g1w = (const float*)d_in[9];
  const float* g1b = (const float*)d_in[10];
  const float* g1a = (const float*)d_in[11];
  const float* g2w = (const float*)d_in[12];
  const float* g2b = (const float*)d_in[13];
  const float* g2a = (const float*)d_in[14];

  char* p = (char*)d_ws;
  auto alloc = [&](size_t bytes) -> void* {
    void* r = (void*)p;
    p += (bytes + 255) & ~(size_t)255;
    return r;
  };
  float* deg      = (float*)alloc(NN*4);
  int*   cnt      = (int*)  alloc(NN*4);
  int*   row_ptr  = (int*)  alloc((NN+1)*4);
  int*   cursor   = (int*)  alloc(NN*4);
  int*   btot     = (int*)  alloc(256*4);
  int*   boff     = (int*)  alloc(256*4);
  int*   csr_src  = (int*)  alloc((size_t)NE*4);
  float* csr_nrm  = (float*)alloc((size_t)NE*4);
  f4*    h1       = (f4*)   alloc((size_t)NN*16);
  f4*    h2       = (f4*)   alloc((size_t)NN*16);
  f4*    h3       = (f4*)   alloc((size_t)NN*16);
  f4*    p0       = (f4*)   alloc((size_t)NN*16);
  f4*    p1       = (f4*)   alloc((size_t)NN*16);
  f4*    p2       = (f4*)   alloc((size_t)NN*16);
  f4*    p3       = (f4*)   alloc((size_t)NN*16);
  f4*    t1       = (f4*)   alloc((size_t)NN*16);
  f4*    t2       = (f4*)   alloc((size_t)NN*16);
  float* stats    = (float*)alloc(1024*4);
  float* s1 = stats, *s2 = stats + 512;
  float* scb      = (float*)alloc(HD*4);
  float* shb      = (float*)alloc(HD*4);
  float* pS       = (float*)alloc((size_t)STATS_NB*HD*4);   // 1 MB
  float* pQ       = (float*)alloc((size_t)STATS_NB*HD*4);   // 1 MB
  u16*   W2T      = (u16*)  alloc((size_t)4*HD*HD*2);       // 2 MB
  // big buffers: 3 x 51.2 MB bf16  (~175 MB total)
  u16*   bfA      = (u16*)  alloc((size_t)NN*HD*2);
  u16*   bfB      = (u16*)  alloc((size_t)NN*HD*2);
  u16*   bfC      = (u16*)  alloc((size_t)NN*HD*2);   // C partial then act2

  const int TPB = 256;
  int gridE = (NE + TPB - 1)/TPB;
  int gridN = (NN + TPB - 1)/TPB;
  int gridIp = (int)(((size_t)NN*HD/8 + 255)/256);
  int gridP = (NN + 3)/4;

  // CSR + norm
  hipMemsetAsync(deg, 0, NN*4, stream);
  hipMemsetAsync(cnt, 0, NN*4, stream);
  k_deg<<<gridE, TPB, 0, stream>>>(dst, w, deg, cnt);
  k_dinv<<<gridN, TPB, 0, stream>>>(deg);
  k_scanA<<<NBCHUNK, 256, 0, stream>>>(cnt, row_ptr, btot);
  k_scanB<<<1, 256, 0, stream>>>(btot, boff);
  k_scanC<<<NBCHUNK, 256, 0, stream>>>(row_ptr, boff);
  hipMemsetAsync(cursor, 0, NN*4, stream);
  k_fill<<<gridE, TPB, 0, stream>>>(src, dst, w, deg, row_ptr, cursor, csr_src, csr_nrm);
  k_w2t<<<(4*HD*HD + 255)/256, 256, 0, stream>>>(W2, W2T);

  // Layer 1: hops, then fused combine+ELU+stats -> bf16 act (pre-norm) in bfA
  k_prop4<<<gridN, TPB, 0, stream>>>(row_ptr, csr_src, csr_nrm, (const f4*)x, nullptr, nullptr, nullptr, h1);
  k_prop4<<<gridN, TPB, 0, stream>>>(row_ptr, csr_src, csr_nrm, h1, nullptr, nullptr, nullptr, h2);
  k_prop4<<<gridN, TPB, 0, stream>>>(row_ptr, csr_src, csr_nrm, h2, nullptr, nullptr, nullptr, h3);
  k_combine1s<<<STATS_NB, 256, 0, stream>>>((const f4*)x, h1, h2, h3, W1, b1, bfA, pS, pQ);
  k_reduce<<<2, 256, 0, stream>>>(pS, pQ, STATS_NB, s1, s2);
  k_affine<<<2, 256, 0, stream>>>(s1, s2, g1w, g1b, g1a, scb, shb);
  k_norm_ip<<<gridIp, 256, 0, stream>>>(bfA, scb, shb);

  // Layer 2: h0=bfA, h1=prop(h0)=bfB -> GEMM1 writes Cbf (bf16 partial);
  //          h2=prop(h1)=bfA, h3=prop(h2)=bfB -> GEMM2 accumulates + bias+ELU+stats in-place
  k_prop512_bf<<<gridP, 256, 0, stream>>>(row_ptr, csr_src, csr_nrm, bfA, bfB);
  k_gemm2<0><<<GRIDM*4, 256, 0, stream>>>(bfA, bfB, W2T, W2T + (size_t)HD*HD,
                                          bfC, nullptr, nullptr, nullptr, NN);
  k_prop512_bf<<<gridP, 256, 0, stream>>>(row_ptr, csr_src, csr_nrm, bfB, bfA);
  k_prop512_bf<<<gridP, 256, 0, stream>>>(row_ptr, csr_src, csr_nrm, bfA, bfB);
  k_gemm2<1><<<GRIDM*4, 256, 0, stream>>>(bfA, bfB, W2T + 2*(size_t)HD*HD, W2T + 3*(size_t)HD*HD,
                                          bfC, b2, pS, pQ, NN);

  // GraphNorm 2 affine from GEMM-fused partials
  k_reduce<<<2, 256, 0, stream>>>(pS, pQ, GRIDM, s1, s2);
  k_affine<<<2, 256, 0, stream>>>(s1, s2, g2w, g2b, g2a, scb, shb);

  // Layer 3: fused-norm narrow linears, then Horner with width-4 propagations
  k_lin3<<<gridP, 256, 0, stream>>>(bfC, scb, shb, W3, p0, p1, p2, p3);
  k_prop4<<<gridN, TPB, 0, stream>>>(row_ptr, csr_src, csr_nrm, p3, nullptr, nullptr, nullptr, t1);
  k_prop4<<<gridN, TPB, 0, stream>>>(row_ptr, csr_src, csr_nrm, p2, t1, nullptr, nullptr, t2);
  k_prop4<<<gridN, TPB, 0, stream>>>(row_ptr, csr_src, csr_nrm, p1, t2, p0, b3, (f4*)d_out);
}